// Round 5
// baseline (954.059 us; speedup 1.0000x reference)
//
#include <hip/hip_runtime.h>
#include <math.h>

#define B_ 512
#define L_ 100
#define D_ 1024
#define POS_DIM_ 50
#define GM 51200
#define GN 1024
#define GK 1024
#define LDT 40   // padded LDS row stride (halfwords) for A tiles in gemm_hWn

typedef _Float16 half8 __attribute__((ext_vector_type(8)));
typedef _Float16 half4 __attribute__((ext_vector_type(4)));
typedef float floatx4 __attribute__((ext_vector_type(4)));

// ---------- fast device math ----------
__device__ __forceinline__ float fast_tanh(float x) {
    float e = __expf(2.0f * x);
    return 1.0f - 2.0f * __builtin_amdgcn_rcpf(e + 1.0f);
}
__device__ __forceinline__ float fast_sigmoid(float x) {
    return __builtin_amdgcn_rcpf(1.0f + __expf(-x));
}

// async global->LDS, 16B per lane; lds base must be wave-uniform
__device__ __forceinline__ void gll16(const void* g, void* l) {
    __builtin_amdgcn_global_load_lds(
        (const __attribute__((address_space(1))) void*)g,
        (__attribute__((address_space(3))) void*)l, 16, 0, 0);
}

// ---------- Kernel 1: docs (masked mean) + f16 hi/lo split of docs ----------
__global__ __launch_bounds__(256) void docs_kernel(
    const float* __restrict__ sent, const int* __restrict__ doc_lens,
    _Float16* __restrict__ docs_hi, _Float16* __restrict__ docs_lo)
{
    int b = blockIdx.x;
    int tid = threadIdx.x;
    int len = doc_lens[b];
    float inv = 1.0f / (float)len;
    const float* p = sent + (size_t)b * L_ * D_ + tid * 4;
    float4 acc = {0.f, 0.f, 0.f, 0.f};
    float4 acc2 = {0.f, 0.f, 0.f, 0.f};
    int l = 0;
    for (; l + 1 < len; l += 2) {
        float4 v0 = *(const float4*)(p + (size_t)l * D_);
        float4 v1 = *(const float4*)(p + (size_t)(l + 1) * D_);
        acc.x += v0.x; acc.y += v0.y; acc.z += v0.z; acc.w += v0.w;
        acc2.x += v1.x; acc2.y += v1.y; acc2.z += v1.z; acc2.w += v1.w;
    }
    if (l < len) {
        float4 v0 = *(const float4*)(p + (size_t)l * D_);
        acc.x += v0.x; acc.y += v0.y; acc.z += v0.z; acc.w += v0.w;
    }
    acc.x += acc2.x; acc.y += acc2.y; acc.z += acc2.z; acc.w += acc2.w;
    float a[4] = {acc.x * inv, acc.y * inv, acc.z * inv, acc.w * inv};
    half4 h, lo;
    #pragma unroll
    for (int i = 0; i < 4; ++i) {
        _Float16 hi = (_Float16)a[i];
        h[i] = hi;
        lo[i] = (_Float16)(a[i] - (float)hi);
    }
    *(half4*)(docs_hi + (size_t)b * D_ + tid * 4) = h;
    *(half4*)(docs_lo + (size_t)b * D_ + tid * 4) = lo;
}

// ---------- Kernel 2: tiny embedding dots ----------
__global__ void emb_kernel(const float* __restrict__ abs_emb,
                           const float* __restrict__ rel_emb,
                           const float* __restrict__ abs_w,
                           const float* __restrict__ rel_w,
                           float* __restrict__ abs_p, float* __restrict__ rel_vals)
{
    int t = threadIdx.x;
    if (t < L_) {
        float a = 0.f;
        for (int j = 0; j < POS_DIM_; ++j) a += abs_emb[t * POS_DIM_ + j] * abs_w[j];
        abs_p[t] = a;
    }
    if (t < 10) {
        float r = 0.f;
        for (int j = 0; j < POS_DIM_; ++j) r += rel_emb[t * POS_DIM_ + j] * rel_w[j];
        rel_vals[t] = r;
    }
}

// ---------- Kernel 3: elementwise f16 hi/lo split of fc_w and sal_w ----------
__global__ __launch_bounds__(256) void wsplit_kernel(
    const float* __restrict__ fc_w, const float* __restrict__ sal_w,
    _Float16* __restrict__ fcw_hi, _Float16* __restrict__ fcw_lo,
    _Float16* __restrict__ salw_hi, _Float16* __restrict__ salw_lo)
{
    int id = blockIdx.x * 256 + threadIdx.x;
    int base = id * 4;
    const int NN = D_ * D_;
    const float* src; _Float16* dh; _Float16* dl; int off;
    if (base < NN) { src = fc_w; dh = fcw_hi; dl = fcw_lo; off = base; }
    else           { src = sal_w; dh = salw_hi; dl = salw_lo; off = base - NN; }
    float4 v = *(const float4*)(src + off);
    float a[4] = {v.x, v.y, v.z, v.w};
    half4 h, lo;
    #pragma unroll
    for (int i = 0; i < 4; ++i) {
        _Float16 hi = (_Float16)a[i];
        h[i] = hi;
        lo[i] = (_Float16)(a[i] - (float)hi);
    }
    *(half4*)(dh + off) = h;
    *(half4*)(dl + off) = lo;
}

// ---------- Kernel 4: transpose + f16 hi/lo split of nov_w ----------
__global__ __launch_bounds__(256) void convert_b(
    const float* __restrict__ B, _Float16* __restrict__ Bt_hi,
    _Float16* __restrict__ Bt_lo)
{
    __shared__ float ld[32][33];
    int k0 = blockIdx.x * 32, n0 = blockIdx.y * 32;
    int r  = threadIdx.x >> 3;
    int c4 = (threadIdx.x & 7) * 4;
    float4 v = *(const float4*)(B + (size_t)(k0 + r) * D_ + n0 + c4);
    ld[r][c4] = v.x; ld[r][c4 + 1] = v.y; ld[r][c4 + 2] = v.z; ld[r][c4 + 3] = v.w;
    __syncthreads();
    half4 h, l;
    #pragma unroll
    for (int i = 0; i < 4; ++i) {
        float x = ld[c4 + i][r];
        _Float16 hi = (_Float16)x;
        h[i] = hi;
        l[i] = (_Float16)(x - (float)hi);
    }
    *(half4*)(Bt_hi + (size_t)(n0 + r) * D_ + k0 + c4) = h;
    *(half4*)(Bt_lo + (size_t)(n0 + r) * D_ + k0 + c4) = l;
}

// ---------- Kernel 5: MFMA 3-pass f16-split GEMM for small GEMMs ----------
// A (hi/lo) [M,K] f16, B (hi/lo) [N,K] f16; all staging via global_load_lds.
// EPI 1: v = tanh(acc+X[n]) -> write f16 hi/lo pair (Oh, Ol)
// EPI 2: v = acc+X[n]       -> write fp32 O
template<int EPI>
__global__ __launch_bounds__(256, 2) void gemm_ms(
    const _Float16* __restrict__ Ah, const _Float16* __restrict__ Al,
    const _Float16* __restrict__ Bh, const _Float16* __restrict__ Bl,
    const float* __restrict__ X, float* __restrict__ O,
    _Float16* __restrict__ Oh, _Float16* __restrict__ Ol)
{
    __shared__ _Float16 sAh[128 * 32];
    __shared__ _Float16 sAl[128 * 32];
    __shared__ _Float16 sBh[128 * 32];
    __shared__ _Float16 sBl[128 * 32];

    int tid = threadIdx.x;
    int wave = tid >> 6, lane = tid & 63;
    int n0 = blockIdx.x * 128, m0 = blockIdx.y * 128;
    int wm = (wave >> 1) * 64, wn = (wave & 1) * 64;
    int tm = lane & 15, quad = lane >> 4;

    floatx4 acc[4][4];
    #pragma unroll
    for (int i = 0; i < 4; ++i)
        #pragma unroll
        for (int j = 0; j < 4; ++j)
            acc[i][j] = (floatx4){0.f, 0.f, 0.f, 0.f};

    int grow = lane >> 2;          // 0..15
    int gcol = (lane & 3) * 8;     // halfword offset
    const _Float16* pAh = Ah + (size_t)(m0 + wave * 32 + grow) * GK + gcol;
    const _Float16* pAl = Al + (size_t)(m0 + wave * 32 + grow) * GK + gcol;
    const _Float16* pBh = Bh + (size_t)(n0 + wave * 32 + grow) * GK + gcol;
    const _Float16* pBl = Bl + (size_t)(n0 + wave * 32 + grow) * GK + gcol;
    _Float16* lAh = sAh + wave * 32 * 32;
    _Float16* lAl = sAl + wave * 32 * 32;
    _Float16* lBh = sBh + wave * 32 * 32;
    _Float16* lBl = sBl + wave * 32 * 32;

    #pragma unroll 1
    for (int k0 = 0; k0 < GK; k0 += 32) {
        __syncthreads();   // previous iteration's fragment reads complete
        gll16(pAh + k0, lAh);
        gll16(pAh + 16 * GK + k0, lAh + 16 * 32);
        gll16(pAl + k0, lAl);
        gll16(pAl + 16 * GK + k0, lAl + 16 * 32);
        gll16(pBh + k0, lBh);
        gll16(pBh + 16 * GK + k0, lBh + 16 * 32);
        gll16(pBl + k0, lBl);
        gll16(pBl + 16 * GK + k0, lBl + 16 * 32);
        __syncthreads();   // drains vmcnt(0): LDS tile ready

        half8 fah[4], fal[4], fbh[4], fbl[4];
        #pragma unroll
        for (int mt = 0; mt < 4; ++mt) {
            int base = (wm + mt * 16 + tm) * 32 + quad * 8;
            fah[mt] = *(const half8*)(sAh + base);
            fal[mt] = *(const half8*)(sAl + base);
        }
        #pragma unroll
        for (int nt = 0; nt < 4; ++nt) {
            int base = (wn + nt * 16 + tm) * 32 + quad * 8;
            fbh[nt] = *(const half8*)(sBh + base);
            fbl[nt] = *(const half8*)(sBl + base);
        }
        #pragma unroll
        for (int mt = 0; mt < 4; ++mt)
            #pragma unroll
            for (int nt = 0; nt < 4; ++nt) {
                acc[mt][nt] = __builtin_amdgcn_mfma_f32_16x16x32_f16(
                    fah[mt], fbh[nt], acc[mt][nt], 0, 0, 0);
                acc[mt][nt] = __builtin_amdgcn_mfma_f32_16x16x32_f16(
                    fah[mt], fbl[nt], acc[mt][nt], 0, 0, 0);
                acc[mt][nt] = __builtin_amdgcn_mfma_f32_16x16x32_f16(
                    fal[mt], fbh[nt], acc[mt][nt], 0, 0, 0);
            }
    }

    #pragma unroll
    for (int mt = 0; mt < 4; ++mt) {
        #pragma unroll
        for (int nt = 0; nt < 4; ++nt) {
            int col = n0 + wn + nt * 16 + tm;
            int rowb = m0 + wm + mt * 16 + quad * 4;
            float xv = X[col];
            #pragma unroll
            for (int r = 0; r < 4; ++r) {
                float v = acc[mt][nt][r];
                if (EPI == 1) {
                    v = tanhf(v + xv);
                    _Float16 hi = (_Float16)v;
                    Oh[(size_t)(rowb + r) * GN + col] = hi;
                    Ol[(size_t)(rowb + r) * GN + col] = (_Float16)(v - (float)hi);
                } else {
                    O[(size_t)(rowb + r) * GN + col] = v + xv;
                }
            }
        }
    }
}

// ---------- Kernel 6: MFMA f16-split GEMM: hWn = sent @ nov_w ----------
// Round-2 A-staging (LDS, 20.5 KB total) + B DIRECT global->register
// fragment loads: Bt hi+lo is 4 MiB, L2-resident per XCD, so each wave
// loads its 8 B-half8 fragments straight from global at iteration top;
// by MFMA time (after A split + 2 barriers) they are back from L2.
// Removes the B gll DMA + its vmcnt drain at the barrier and all B-side
// LDS bank conflicts. Cost: ~2x B L2 traffic (~10 TB/s << 34 TB/s L2).
__global__ __launch_bounds__(256, 2) void gemm_hWn(
    const float* __restrict__ A, const _Float16* __restrict__ Bt_hi,
    const _Float16* __restrict__ Bt_lo, float* __restrict__ C)
{
    __shared__ _Float16 As_hi[128 * LDT];
    __shared__ _Float16 As_lo[128 * LDT];

    int tid  = threadIdx.x;
    int wave = tid >> 6, lane = tid & 63;
    int d = blockIdx.x;
    int islab = d & 7, nblk = (d >> 3) & 7, g = d >> 6;
    int m0 = (g * 8 + islab) * 128;
    int n0 = nblk * 128;
    int wm = (wave >> 1) * 64, wn = (wave & 1) * 64;
    int tm   = lane & 15;
    int quad = lane >> 4;

    floatx4 acc[4][4];
    #pragma unroll
    for (int i = 0; i < 4; ++i)
        #pragma unroll
        for (int j = 0; j < 4; ++j)
            acc[i][j] = (floatx4){0.f, 0.f, 0.f, 0.f};

    // A staging: thread covers (row, 16-elem k-half)
    int sr = tid >> 1;
    int sh = tid & 1;
    const float* Ap = A + (size_t)(m0 + sr) * GK + sh * 16;
    int sbase = sr * LDT + sh * 16;

    // B direct per-lane fragment base: row = n0 + wn + nt*16 + tm, col = quad*8
    const _Float16* pBh = Bt_hi + (size_t)(n0 + wn + tm) * GK + quad * 8;
    const _Float16* pBl = Bt_lo + (size_t)(n0 + wn + tm) * GK + quad * 8;

    #pragma unroll 1
    for (int k0 = 0; k0 < GK; k0 += 32) {
        // ---- issue all global loads for this tile up front ----
        float4 a0 = *(const float4*)(Ap + k0);
        float4 a1 = *(const float4*)(Ap + k0 + 4);
        float4 a2 = *(const float4*)(Ap + k0 + 8);
        float4 a3 = *(const float4*)(Ap + k0 + 12);

        half8 fb_hi[4], fb_lo[4];
        #pragma unroll
        for (int nt = 0; nt < 4; ++nt) {
            fb_hi[nt] = *(const half8*)(pBh + (size_t)nt * 16 * GK + k0);
            fb_lo[nt] = *(const half8*)(pBl + (size_t)nt * 16 * GK + k0);
        }

        // ---- split A to f16 hi/lo (waits only on a0..a3) ----
        half8 ah0, ah1, al0, al1;
        float af[16] = {a0.x, a0.y, a0.z, a0.w, a1.x, a1.y, a1.z, a1.w,
                        a2.x, a2.y, a2.z, a2.w, a3.x, a3.y, a3.z, a3.w};
        #pragma unroll
        for (int i = 0; i < 8; ++i) {
            _Float16 h = (_Float16)af[i];
            ah0[i] = h;
            al0[i] = (_Float16)(af[i] - (float)h);
        }
        #pragma unroll
        for (int i = 0; i < 8; ++i) {
            _Float16 h = (_Float16)af[8 + i];
            ah1[i] = h;
            al1[i] = (_Float16)(af[8 + i] - (float)h);
        }

        __syncthreads();   // previous iteration's A-fragment reads complete
        *(half8*)(As_hi + sbase)     = ah0;
        *(half8*)(As_hi + sbase + 8) = ah1;
        *(half8*)(As_lo + sbase)     = al0;
        *(half8*)(As_lo + sbase + 8) = al1;
        __syncthreads();   // A tile visible (lgkm drained)

        // ---- A fragments from LDS, MFMA with in-register B ----
        half8 fa_hi[4], fa_lo[4];
        #pragma unroll
        for (int mt = 0; mt < 4; ++mt) {
            int row = (wm + mt * 16 + tm) * LDT + quad * 8;
            fa_hi[mt] = *(const half8*)(As_hi + row);
            fa_lo[mt] = *(const half8*)(As_lo + row);
        }
        #pragma unroll
        for (int mt = 0; mt < 4; ++mt)
            #pragma unroll
            for (int nt = 0; nt < 4; ++nt) {
                acc[mt][nt] = __builtin_amdgcn_mfma_f32_16x16x32_f16(
                    fa_hi[mt], fb_hi[nt], acc[mt][nt], 0, 0, 0);
                acc[mt][nt] = __builtin_amdgcn_mfma_f32_16x16x32_f16(
                    fa_hi[mt], fb_lo[nt], acc[mt][nt], 0, 0, 0);
                acc[mt][nt] = __builtin_amdgcn_mfma_f32_16x16x32_f16(
                    fa_lo[mt], fb_hi[nt], acc[mt][nt], 0, 0, 0);
            }
    }

    #pragma unroll
    for (int mt = 0; mt < 4; ++mt) {
        #pragma unroll
        for (int nt = 0; nt < 4; ++nt) {
            int col = n0 + wn + nt * 16 + tm;
            int rowb = m0 + wm + mt * 16 + quad * 4;
            #pragma unroll
            for (int r = 0; r < 4; ++r)
                C[(size_t)(rowb + r) * GN + col] = acc[mt][nt][r];
        }
    }
}

// ---------- Kernel 7: scan — one wave per batch, all-register ----------
// All state in NAMED float4 registers (no arrays, no pointer-param lambdas):
// rule #20 — runtime-indexed/pointer-passed private arrays go to scratch.
__global__ __launch_bounds__(64) void scan_kernel(
    const float* __restrict__ sent, const float* __restrict__ hWn,
    const float* __restrict__ u, const float* __restrict__ abs_p,
    const float* __restrict__ rel_vals, const float* __restrict__ bias,
    const int* __restrict__ doc_lens, float* __restrict__ out)
{
    int b = blockIdx.x;
    int lane = threadIdx.x;
    int len = doc_lens[b];
    float lenf = (float)len;

    for (int l = len + lane; l < L_; l += 64) out[b * L_ + l] = 0.f;

    // lane owns cols {lane*4 + j*256 : j=0..3, +0..3}
    const float* ub = u + (size_t)b * D_ + lane * 4;
    float4 ur0 = *(const float4*)(ub);
    float4 ur1 = *(const float4*)(ub + 256);
    float4 ur2 = *(const float4*)(ub + 512);
    float4 ur3 = *(const float4*)(ub + 768);

    float4 s0 = {0.f,0.f,0.f,0.f}, s1 = {0.f,0.f,0.f,0.f};
    float4 s2 = {0.f,0.f,0.f,0.f}, s3 = {0.f,0.f,0.f,0.f};

    const float* sb = sent + (size_t)b * L_ * D_ + lane * 4;
    const float* wb = hWn  + (size_t)b * L_ * D_ + lane * 4;
    float biasv = bias[0];

    float4 hA0, hA1, hA2, hA3, wA0, wA1, wA2, wA3;
    float4 hB0, hB1, hB2, hB3, wB0, wB1, wB2, wB3;

#define LOADROW(row, H0,H1,H2,H3, W0,W1,W2,W3) do { \
    const float* ph_ = sb + (size_t)(row) * D_; \
    const float* pw_ = wb + (size_t)(row) * D_; \
    H0 = *(const float4*)(ph_);       W0 = *(const float4*)(pw_); \
    H1 = *(const float4*)(ph_ + 256); W1 = *(const float4*)(pw_ + 256); \
    H2 = *(const float4*)(ph_ + 512); W2 = *(const float4*)(pw_ + 512); \
    H3 = *(const float4*)(ph_ + 768); W3 = *(const float4*)(pw_ + 768); \
} while (0)

#define DOT4(acc_, X, Y) do { \
    acc_ = fmaf((X).x, (Y).x, acc_); acc_ = fmaf((X).y, (Y).y, acc_); \
    acc_ = fmaf((X).z, (Y).z, acc_); acc_ = fmaf((X).w, (Y).w, acc_); \
} while (0)

#define STEP(t, H0,H1,H2,H3, W0,W1,W2,W3) do { \
    float4 t0_, t1_, t2_, t3_; \
    t0_.x = fast_tanh(s0.x); t0_.y = fast_tanh(s0.y); t0_.z = fast_tanh(s0.z); t0_.w = fast_tanh(s0.w); \
    t1_.x = fast_tanh(s1.x); t1_.y = fast_tanh(s1.y); t1_.z = fast_tanh(s1.z); t1_.w = fast_tanh(s1.w); \
    t2_.x = fast_tanh(s2.x); t2_.y = fast_tanh(s2.y); t2_.z = fast_tanh(s2.z); t2_.w = fast_tanh(s2.w); \
    t3_.x = fast_tanh(s3.x); t3_.y = fast_tanh(s3.y); t3_.z = fast_tanh(s3.z); t3_.w = fast_tanh(s3.w); \
    float r1_ = 0.f, r2_ = 0.f; \
    DOT4(r1_, W0, t0_); DOT4(r1_, W1, t1_); DOT4(r1_, W2, t2_); DOT4(r1_, W3, t3_); \
    DOT4(r2_, H0, ur0); DOT4(r2_, H1, ur1); DOT4(r2_, H2, ur2); DOT4(r2_, H3, ur3); \
    _Pragma("unroll") \
    for (int off_ = 32; off_; off_ >>= 1) { \
        r1_ += __shfl_xor(r1_, off_); \
        r2_ += __shfl_xor(r2_, off_); \
    } \
    int ridx_ = (int)rintf((float)((t) + 1) * 9.0f / lenf); \
    ridx_ = min(max(ridx_, 0), 9); \
    float pre_ = r2_ + abs_p[(t)] + rel_vals[ridx_] + biasv - r1_; \
    float prob_ = fast_sigmoid(pre_); \
    if (lane == 0) out[b * L_ + (t)] = prob_; \
    s0.x = fmaf(prob_, (H0).x, s0.x); s0.y = fmaf(prob_, (H0).y, s0.y); \
    s0.z = fmaf(prob_, (H0).z, s0.z); s0.w = fmaf(prob_, (H0).w, s0.w); \
    s1.x = fmaf(prob_, (H1).x, s1.x); s1.y = fmaf(prob_, (H1).y, s1.y); \
    s1.z = fmaf(prob_, (H1).z, s1.z); s1.w = fmaf(prob_, (H1).w, s1.w); \
    s2.x = fmaf(prob_, (H2).x, s2.x); s2.y = fmaf(prob_, (H2).y, s2.y); \
    s2.z = fmaf(prob_, (H2).z, s2.z); s2.w = fmaf(prob_, (H2).w, s2.w); \
    s3.x = fmaf(prob_, (H3).x, s3.x); s3.y = fmaf(prob_, (H3).y, s3.y); \
    s3.z = fmaf(prob_, (H3).z, s3.z); s3.w = fmaf(prob_, (H3).w, s3.w); \
} while (0)

    LOADROW(0, hA0,hA1,hA2,hA3, wA0,wA1,wA2,wA3);
    int t = 0;
    while (true) {
        int tn = min(t + 1, len - 1);
        LOADROW(tn, hB0,hB1,hB2,hB3, wB0,wB1,wB2,wB3);
        STEP(t, hA0,hA1,hA2,hA3, wA0,wA1,wA2,wA3);
        ++t; if (t >= len) break;
        tn = min(t + 1, len - 1);
        LOADROW(tn, hA0,hA1,hA2,hA3, wA0,wA1,wA2,wA3);
        STEP(t, hB0,hB1,hB2,hB3, wB0,wB1,wB2,wB3);
        ++t; if (t >= len) break;
    }
#undef LOADROW
#undef DOT4
#undef STEP
}

// ---------- launch ----------
extern "C" void kernel_launch(void* const* d_in, const int* in_sizes, int n_in,
                              void* d_out, int out_size, void* d_ws, size_t ws_size,
                              hipStream_t stream)
{
    const float* sent      = (const float*)d_in[0];
    const float* fc_w      = (const float*)d_in[1];
    const float* fc_b      = (const float*)d_in[2];
    const float* content_w = (const float*)d_in[3];
    const float* sal_w     = (const float*)d_in[4];
    const float* nov_w     = (const float*)d_in[5];
    const float* abs_emb   = (const float*)d_in[6];
    const float* rel_emb   = (const float*)d_in[7];
    const float* abs_w     = (const float*)d_in[8];
    const float* rel_w     = (const float*)d_in[9];
    const float* bias      = (const float*)d_in[10];
    const int*   doc_lens  = (const int*)d_in[11];
    float* out = (float*)d_out;

    char* ws = (char*)d_ws;
    const size_t MB = 1024 * 1024;
    _Float16* docs_hi = (_Float16*)(ws);             // 1 MiB
    _Float16* docs_lo = (_Float16*)(ws + 1 * MB);    // 1 MiB
    _Float16* dv_hi   = (_Float16*)(ws + 2 * MB);    // 1 MiB
    _Float16* dv_lo   = (_Float16*)(ws + 3 * MB);    // 1 MiB
    float*    u       = (float*)(ws + 4 * MB);       // 2 MiB
    float*    abs_p   = (float*)(ws + 6 * MB);
    float*    rel_vals= (float*)(ws + 6 * MB + 512);
    _Float16* fcw_hi  = (_Float16*)(ws + 7 * MB);    // 2 MiB
    _Float16* fcw_lo  = (_Float16*)(ws + 9 * MB);    // 2 MiB
    _Float16* salw_hi = (_Float16*)(ws + 11 * MB);   // 2 MiB
    _Float16* salw_lo = (_Float16*)(ws + 13 * MB);   // 2 MiB
    _Float16* Bt_hi   = (_Float16*)(ws + 15 * MB);   // 2 MiB
    _Float16* Bt_lo   = (_Float16*)(ws + 17 * MB);   // 2 MiB
    float*    hWn     = (float*)(ws + 20 * MB);      // 200 MiB

    // 1) docs masked mean + split
    docs_kernel<<<dim3(B_), 256, 0, stream>>>(sent, doc_lens, docs_hi, docs_lo);

    // 2) embedding dots
    emb_kernel<<<dim3(1), 128, 0, stream>>>(abs_emb, rel_emb, abs_w, rel_w, abs_p, rel_vals);

    // 3) split fc_w / sal_w (already [N,K] layout)
    wsplit_kernel<<<dim3(2 * D_ * D_ / (256 * 4)), 256, 0, stream>>>(
        fc_w, sal_w, fcw_hi, fcw_lo, salw_hi, salw_lo);

    // 4) transpose + split nov_w
    convert_b<<<dim3(32, 32), 256, 0, stream>>>(nov_w, Bt_hi, Bt_lo);

    // 5) hWn = sent @ nov_w  (XCD-swizzled 1D grid: 50 groups * 64 blocks)
    gemm_hWn<<<dim3(3200), 256, 0, stream>>>(sent, Bt_hi, Bt_lo, hWn);

    // 6) doc_vec = tanh(docs @ fc_w^T + fc_b) -> f16 pair
    gemm_ms<1><<<dim3(D_ / 128, B_ / 128), 256, 0, stream>>>(
        docs_hi, docs_lo, fcw_hi, fcw_lo, fc_b, nullptr, dv_hi, dv_lo);

    // 7) u = doc_vec @ sal_w^T + content_w -> fp32
    gemm_ms<2><<<dim3(D_ / 128, B_ / 128), 256, 0, stream>>>(
        dv_hi, dv_lo, salw_hi, salw_lo, content_w, u, nullptr, nullptr);

    // 8) scan: one wave per batch
    scan_kernel<<<dim3(B_), 64, 0, stream>>>(
        sent, hWn, u, abs_p, rel_vals, bias, doc_lens, out);
}

// Round 6
// 813.696 us; speedup vs baseline: 1.1725x; 1.1725x over previous
//
#include <hip/hip_runtime.h>
#include <math.h>

#define B_ 512
#define L_ 100
#define D_ 1024
#define POS_DIM_ 50
#define GM 51200
#define GN 1024
#define GK 1024
#define LDT 40   // padded LDS row stride (halfwords) for A tiles in gemm_hWn

typedef _Float16 half8 __attribute__((ext_vector_type(8)));
typedef _Float16 half4 __attribute__((ext_vector_type(4)));
typedef float floatx4 __attribute__((ext_vector_type(4)));

// ---------- fast device math ----------
__device__ __forceinline__ float fast_tanh(float x) {
    float e = __expf(2.0f * x);
    return 1.0f - 2.0f * __builtin_amdgcn_rcpf(e + 1.0f);
}
__device__ __forceinline__ float fast_sigmoid(float x) {
    return __builtin_amdgcn_rcpf(1.0f + __expf(-x));
}

// async global->LDS, 16B per lane; lds base must be wave-uniform
__device__ __forceinline__ void gll16(const void* g, void* l) {
    __builtin_amdgcn_global_load_lds(
        (const __attribute__((address_space(1))) void*)g,
        (__attribute__((address_space(3))) void*)l, 16, 0, 0);
}

// ---------- Kernel 1: docs (masked mean) + f16 hi/lo split of docs ----------
__global__ __launch_bounds__(256) void docs_kernel(
    const float* __restrict__ sent, const int* __restrict__ doc_lens,
    _Float16* __restrict__ docs_hi, _Float16* __restrict__ docs_lo)
{
    int b = blockIdx.x;
    int tid = threadIdx.x;
    int len = doc_lens[b];
    float inv = 1.0f / (float)len;
    const float* p = sent + (size_t)b * L_ * D_ + tid * 4;
    float4 acc = {0.f, 0.f, 0.f, 0.f};
    float4 acc2 = {0.f, 0.f, 0.f, 0.f};
    int l = 0;
    for (; l + 1 < len; l += 2) {
        float4 v0 = *(const float4*)(p + (size_t)l * D_);
        float4 v1 = *(const float4*)(p + (size_t)(l + 1) * D_);
        acc.x += v0.x; acc.y += v0.y; acc.z += v0.z; acc.w += v0.w;
        acc2.x += v1.x; acc2.y += v1.y; acc2.z += v1.z; acc2.w += v1.w;
    }
    if (l < len) {
        float4 v0 = *(const float4*)(p + (size_t)l * D_);
        acc.x += v0.x; acc.y += v0.y; acc.z += v0.z; acc.w += v0.w;
    }
    acc.x += acc2.x; acc.y += acc2.y; acc.z += acc2.z; acc.w += acc2.w;
    float a[4] = {acc.x * inv, acc.y * inv, acc.z * inv, acc.w * inv};
    half4 h, lo;
    #pragma unroll
    for (int i = 0; i < 4; ++i) {
        _Float16 hi = (_Float16)a[i];
        h[i] = hi;
        lo[i] = (_Float16)(a[i] - (float)hi);
    }
    *(half4*)(docs_hi + (size_t)b * D_ + tid * 4) = h;
    *(half4*)(docs_lo + (size_t)b * D_ + tid * 4) = lo;
}

// ---------- Kernel 2: tiny embedding dots ----------
__global__ void emb_kernel(const float* __restrict__ abs_emb,
                           const float* __restrict__ rel_emb,
                           const float* __restrict__ abs_w,
                           const float* __restrict__ rel_w,
                           float* __restrict__ abs_p, float* __restrict__ rel_vals)
{
    int t = threadIdx.x;
    if (t < L_) {
        float a = 0.f;
        for (int j = 0; j < POS_DIM_; ++j) a += abs_emb[t * POS_DIM_ + j] * abs_w[j];
        abs_p[t] = a;
    }
    if (t < 10) {
        float r = 0.f;
        for (int j = 0; j < POS_DIM_; ++j) r += rel_emb[t * POS_DIM_ + j] * rel_w[j];
        rel_vals[t] = r;
    }
}

// ---------- Kernel 3: elementwise f16 hi/lo split of fc_w and sal_w ----------
__global__ __launch_bounds__(256) void wsplit_kernel(
    const float* __restrict__ fc_w, const float* __restrict__ sal_w,
    _Float16* __restrict__ fcw_hi, _Float16* __restrict__ fcw_lo,
    _Float16* __restrict__ salw_hi, _Float16* __restrict__ salw_lo)
{
    int id = blockIdx.x * 256 + threadIdx.x;
    int base = id * 4;
    const int NN = D_ * D_;
    const float* src; _Float16* dh; _Float16* dl; int off;
    if (base < NN) { src = fc_w; dh = fcw_hi; dl = fcw_lo; off = base; }
    else           { src = sal_w; dh = salw_hi; dl = salw_lo; off = base - NN; }
    float4 v = *(const float4*)(src + off);
    float a[4] = {v.x, v.y, v.z, v.w};
    half4 h, lo;
    #pragma unroll
    for (int i = 0; i < 4; ++i) {
        _Float16 hi = (_Float16)a[i];
        h[i] = hi;
        lo[i] = (_Float16)(a[i] - (float)hi);
    }
    *(half4*)(dh + off) = h;
    *(half4*)(dl + off) = lo;
}

// ---------- Kernel 4: transpose + f16 hi/lo split of nov_w ----------
__global__ __launch_bounds__(256) void convert_b(
    const float* __restrict__ B, _Float16* __restrict__ Bt_hi,
    _Float16* __restrict__ Bt_lo)
{
    __shared__ float ld[32][33];
    int k0 = blockIdx.x * 32, n0 = blockIdx.y * 32;
    int r  = threadIdx.x >> 3;
    int c4 = (threadIdx.x & 7) * 4;
    float4 v = *(const float4*)(B + (size_t)(k0 + r) * D_ + n0 + c4);
    ld[r][c4] = v.x; ld[r][c4 + 1] = v.y; ld[r][c4 + 2] = v.z; ld[r][c4 + 3] = v.w;
    __syncthreads();
    half4 h, l;
    #pragma unroll
    for (int i = 0; i < 4; ++i) {
        float x = ld[c4 + i][r];
        _Float16 hi = (_Float16)x;
        h[i] = hi;
        l[i] = (_Float16)(x - (float)hi);
    }
    *(half4*)(Bt_hi + (size_t)(n0 + r) * D_ + k0 + c4) = h;
    *(half4*)(Bt_lo + (size_t)(n0 + r) * D_ + k0 + c4) = l;
}

// ---------- Kernel 5: MFMA 3-pass f16-split GEMM for small GEMMs ----------
// A (hi/lo) [M,K] f16, B (hi/lo) [N,K] f16; all staging via global_load_lds.
// EPI 1: v = tanh(acc+X[n]) -> write f16 hi/lo pair (Oh, Ol)
// EPI 2: v = acc+X[n]       -> write fp32 O
template<int EPI>
__global__ __launch_bounds__(256, 2) void gemm_ms(
    const _Float16* __restrict__ Ah, const _Float16* __restrict__ Al,
    const _Float16* __restrict__ Bh, const _Float16* __restrict__ Bl,
    const float* __restrict__ X, float* __restrict__ O,
    _Float16* __restrict__ Oh, _Float16* __restrict__ Ol)
{
    __shared__ _Float16 sAh[128 * 32];
    __shared__ _Float16 sAl[128 * 32];
    __shared__ _Float16 sBh[128 * 32];
    __shared__ _Float16 sBl[128 * 32];

    int tid = threadIdx.x;
    int wave = tid >> 6, lane = tid & 63;
    int n0 = blockIdx.x * 128, m0 = blockIdx.y * 128;
    int wm = (wave >> 1) * 64, wn = (wave & 1) * 64;
    int tm = lane & 15, quad = lane >> 4;

    floatx4 acc[4][4];
    #pragma unroll
    for (int i = 0; i < 4; ++i)
        #pragma unroll
        for (int j = 0; j < 4; ++j)
            acc[i][j] = (floatx4){0.f, 0.f, 0.f, 0.f};

    int grow = lane >> 2;          // 0..15
    int gcol = (lane & 3) * 8;     // halfword offset
    const _Float16* pAh = Ah + (size_t)(m0 + wave * 32 + grow) * GK + gcol;
    const _Float16* pAl = Al + (size_t)(m0 + wave * 32 + grow) * GK + gcol;
    const _Float16* pBh = Bh + (size_t)(n0 + wave * 32 + grow) * GK + gcol;
    const _Float16* pBl = Bl + (size_t)(n0 + wave * 32 + grow) * GK + gcol;
    _Float16* lAh = sAh + wave * 32 * 32;
    _Float16* lAl = sAl + wave * 32 * 32;
    _Float16* lBh = sBh + wave * 32 * 32;
    _Float16* lBl = sBl + wave * 32 * 32;

    #pragma unroll 1
    for (int k0 = 0; k0 < GK; k0 += 32) {
        __syncthreads();   // previous iteration's fragment reads complete
        gll16(pAh + k0, lAh);
        gll16(pAh + 16 * GK + k0, lAh + 16 * 32);
        gll16(pAl + k0, lAl);
        gll16(pAl + 16 * GK + k0, lAl + 16 * 32);
        gll16(pBh + k0, lBh);
        gll16(pBh + 16 * GK + k0, lBh + 16 * 32);
        gll16(pBl + k0, lBl);
        gll16(pBl + 16 * GK + k0, lBl + 16 * 32);
        __syncthreads();   // drains vmcnt(0): LDS tile ready

        half8 fah[4], fal[4], fbh[4], fbl[4];
        #pragma unroll
        for (int mt = 0; mt < 4; ++mt) {
            int base = (wm + mt * 16 + tm) * 32 + quad * 8;
            fah[mt] = *(const half8*)(sAh + base);
            fal[mt] = *(const half8*)(sAl + base);
        }
        #pragma unroll
        for (int nt = 0; nt < 4; ++nt) {
            int base = (wn + nt * 16 + tm) * 32 + quad * 8;
            fbh[nt] = *(const half8*)(sBh + base);
            fbl[nt] = *(const half8*)(sBl + base);
        }
        #pragma unroll
        for (int mt = 0; mt < 4; ++mt)
            #pragma unroll
            for (int nt = 0; nt < 4; ++nt) {
                acc[mt][nt] = __builtin_amdgcn_mfma_f32_16x16x32_f16(
                    fah[mt], fbh[nt], acc[mt][nt], 0, 0, 0);
                acc[mt][nt] = __builtin_amdgcn_mfma_f32_16x16x32_f16(
                    fah[mt], fbl[nt], acc[mt][nt], 0, 0, 0);
                acc[mt][nt] = __builtin_amdgcn_mfma_f32_16x16x32_f16(
                    fal[mt], fbh[nt], acc[mt][nt], 0, 0, 0);
            }
    }

    #pragma unroll
    for (int mt = 0; mt < 4; ++mt) {
        #pragma unroll
        for (int nt = 0; nt < 4; ++nt) {
            int col = n0 + wn + nt * 16 + tm;
            int rowb = m0 + wm + mt * 16 + quad * 4;
            float xv = X[col];
            #pragma unroll
            for (int r = 0; r < 4; ++r) {
                float v = acc[mt][nt][r];
                if (EPI == 1) {
                    v = tanhf(v + xv);
                    _Float16 hi = (_Float16)v;
                    Oh[(size_t)(rowb + r) * GN + col] = hi;
                    Ol[(size_t)(rowb + r) * GN + col] = (_Float16)(v - (float)hi);
                } else {
                    O[(size_t)(rowb + r) * GN + col] = v + xv;
                }
            }
        }
    }
}

// ---------- Kernel 6: MFMA f16-split GEMM: hWn = sent @ nov_w ----------
// EXACT round-2 structure (333 us known-good; 36.9 KB LDS, 4 blocks/CU;
// r3/r4/r5 rewrites all regressed — do not touch the schedule) PLUS a fused
// per-row dot: pre[m] = sent[m,:]·u[b(m),:] + abs_p[t] + rel_vals[ridx] + bias.
// The af[16] split values already hold the exact fp32 A elements, so the dot
// costs 16 VALU fma/thread/iter (absorbed by the loop's stall slack) + 64B/iter
// of L2-resident u reads. Two staging threads per row combine via shfl_xor(1).
// This removes the h·u dot AND half the serial shfl chain from the scan.
__global__ __launch_bounds__(256, 2) void gemm_hWn(
    const float* __restrict__ A, const _Float16* __restrict__ Bt_hi,
    const _Float16* __restrict__ Bt_lo, float* __restrict__ C,
    const float* __restrict__ u, const float* __restrict__ abs_p,
    const float* __restrict__ rel_vals, const float* __restrict__ bias,
    const int* __restrict__ doc_lens, float* __restrict__ pre)
{
    __shared__ _Float16 As_hi[128 * LDT];
    __shared__ _Float16 As_lo[128 * LDT];
    __shared__ _Float16 Bs_hi[128 * 32];
    __shared__ _Float16 Bs_lo[128 * 32];

    int tid  = threadIdx.x;
    int wave = tid >> 6, lane = tid & 63;
    int d = blockIdx.x;
    int islab = d & 7, nblk = (d >> 3) & 7, g = d >> 6;
    int m0 = (g * 8 + islab) * 128;
    int n0 = nblk * 128;
    int wm = (wave >> 1) * 64, wn = (wave & 1) * 64;
    int tm   = lane & 15;
    int quad = lane >> 4;

    floatx4 acc[4][4];
    #pragma unroll
    for (int i = 0; i < 4; ++i)
        #pragma unroll
        for (int j = 0; j < 4; ++j)
            acc[i][j] = (floatx4){0.f, 0.f, 0.f, 0.f};

    // A staging: thread covers (row, 16-elem k-half)
    int sr = tid >> 1;
    int sh = tid & 1;
    int m  = m0 + sr;
    int bidx = m / 100;               // doc index of this row
    const float* Ap = A + (size_t)m * GK + sh * 16;
    const float* up = u + (size_t)bidx * D_ + sh * 16;
    int sbase = sr * LDT + sh * 16;
    float dotv = 0.f;

    // B staging via gll: wave covers rows [wave*32, wave*32+32)
    int grow = lane >> 2;
    int gswz = ((lane & 3) ^ ((lane >> 3) & 3)) * 8;   // halfword offset
    const _Float16* pBh = Bt_hi + (size_t)(n0 + wave * 32 + grow) * GK + gswz;
    const _Float16* pBl = Bt_lo + (size_t)(n0 + wave * 32 + grow) * GK + gswz;
    _Float16* lBh = Bs_hi + wave * 32 * 32;
    _Float16* lBl = Bs_lo + wave * 32 * 32;

    #pragma unroll 1
    for (int k0 = 0; k0 < GK; k0 += 32) {
        float4 a0 = *(const float4*)(Ap + k0);
        float4 a1 = *(const float4*)(Ap + k0 + 4);
        float4 a2 = *(const float4*)(Ap + k0 + 8);
        float4 a3 = *(const float4*)(Ap + k0 + 12);
        float4 u0 = *(const float4*)(up + k0);
        float4 u1 = *(const float4*)(up + k0 + 4);
        float4 u2 = *(const float4*)(up + k0 + 8);
        float4 u3 = *(const float4*)(up + k0 + 12);

        half8 ah0, ah1, al0, al1;
        float af[16] = {a0.x, a0.y, a0.z, a0.w, a1.x, a1.y, a1.z, a1.w,
                        a2.x, a2.y, a2.z, a2.w, a3.x, a3.y, a3.z, a3.w};
        #pragma unroll
        for (int i = 0; i < 8; ++i) {
            _Float16 h = (_Float16)af[i];
            ah0[i] = h;
            al0[i] = (_Float16)(af[i] - (float)h);
        }
        #pragma unroll
        for (int i = 0; i < 8; ++i) {
            _Float16 h = (_Float16)af[8 + i];
            ah1[i] = h;
            al1[i] = (_Float16)(af[8 + i] - (float)h);
        }
        // fused h·u partial dot (exact fp32 values, L2-resident u)
        dotv = fmaf(a0.x, u0.x, dotv); dotv = fmaf(a0.y, u0.y, dotv);
        dotv = fmaf(a0.z, u0.z, dotv); dotv = fmaf(a0.w, u0.w, dotv);
        dotv = fmaf(a1.x, u1.x, dotv); dotv = fmaf(a1.y, u1.y, dotv);
        dotv = fmaf(a1.z, u1.z, dotv); dotv = fmaf(a1.w, u1.w, dotv);
        dotv = fmaf(a2.x, u2.x, dotv); dotv = fmaf(a2.y, u2.y, dotv);
        dotv = fmaf(a2.z, u2.z, dotv); dotv = fmaf(a2.w, u2.w, dotv);
        dotv = fmaf(a3.x, u3.x, dotv); dotv = fmaf(a3.y, u3.y, dotv);
        dotv = fmaf(a3.z, u3.z, dotv); dotv = fmaf(a3.w, u3.w, dotv);

        __syncthreads();   // previous iteration's fragment reads complete
        // B DMA into LDS (linear dest; source chunk pre-swizzled)
        gll16(pBh + k0, lBh);
        gll16(pBh + 16 * GK + k0, lBh + 16 * 32);
        gll16(pBl + k0, lBl);
        gll16(pBl + 16 * GK + k0, lBl + 16 * 32);
        // A stores
        *(half8*)(As_hi + sbase)     = ah0;
        *(half8*)(As_hi + sbase + 8) = ah1;
        *(half8*)(As_lo + sbase)     = al0;
        *(half8*)(As_lo + sbase + 8) = al1;
        __syncthreads();   // drains vmcnt (gll) + lgkm (stores)

        half8 fa_hi[4], fa_lo[4], fb_hi[4], fb_lo[4];
        #pragma unroll
        for (int mt = 0; mt < 4; ++mt) {
            int row = (wm + mt * 16 + tm) * LDT + quad * 8;
            fa_hi[mt] = *(const half8*)(As_hi + row);
            fa_lo[mt] = *(const half8*)(As_lo + row);
        }
        #pragma unroll
        for (int nt = 0; nt < 4; ++nt) {
            int row = wn + nt * 16 + tm;
            int rbase = row * 32 + ((quad ^ ((row >> 1) & 3)) << 3);
            fb_hi[nt] = *(const half8*)(Bs_hi + rbase);
            fb_lo[nt] = *(const half8*)(Bs_lo + rbase);
        }
        #pragma unroll
        for (int mt = 0; mt < 4; ++mt)
            #pragma unroll
            for (int nt = 0; nt < 4; ++nt) {
                acc[mt][nt] = __builtin_amdgcn_mfma_f32_16x16x32_f16(
                    fa_hi[mt], fb_hi[nt], acc[mt][nt], 0, 0, 0);
                acc[mt][nt] = __builtin_amdgcn_mfma_f32_16x16x32_f16(
                    fa_hi[mt], fb_lo[nt], acc[mt][nt], 0, 0, 0);
                acc[mt][nt] = __builtin_amdgcn_mfma_f32_16x16x32_f16(
                    fa_lo[mt], fb_hi[nt], acc[mt][nt], 0, 0, 0);
            }
    }

    // combine the two k-half partials of each row, add positional terms
    {
        float other = __shfl_xor(dotv, 1);
        float tot = dotv + other;
        if (sh == 0) {
            int t = m - bidx * 100;
            int len = doc_lens[bidx];
            int ridx = (int)rintf((float)(t + 1) * 9.0f / (float)len);
            ridx = min(max(ridx, 0), 9);
            pre[m] = tot + abs_p[t] + rel_vals[ridx] + bias[0];
        }
    }

    #pragma unroll
    for (int mt = 0; mt < 4; ++mt) {
        #pragma unroll
        for (int nt = 0; nt < 4; ++nt) {
            int col = n0 + wn + nt * 16 + tm;
            int rowb = m0 + wm + mt * 16 + quad * 4;
            #pragma unroll
            for (int r = 0; r < 4; ++r)
                C[(size_t)(rowb + r) * GN + col] = acc[mt][nt][r];
        }
    }
}

// ---------- Kernel 7: scan — one wave per batch, all-register ----------
// pre[b,t] (content+sal+positional+bias) is precomputed by gemm_hWn, so the
// per-step serial path is only: tanh(16) -> 16-fma dot -> 6 shfl -> sigmoid
// -> 16-fma state update. Named float4 registers only (rule #20).
__global__ __launch_bounds__(64) void scan_kernel(
    const float* __restrict__ sent, const float* __restrict__ hWn,
    const float* __restrict__ pre, const int* __restrict__ doc_lens,
    float* __restrict__ out)
{
    int b = blockIdx.x;
    int lane = threadIdx.x;
    int len = doc_lens[b];

    for (int l = len + lane; l < L_; l += 64) out[b * L_ + l] = 0.f;

    float4 s0 = {0.f,0.f,0.f,0.f}, s1 = {0.f,0.f,0.f,0.f};
    float4 s2 = {0.f,0.f,0.f,0.f}, s3 = {0.f,0.f,0.f,0.f};

    const float* sb = sent + (size_t)b * L_ * D_ + lane * 4;
    const float* wb = hWn  + (size_t)b * L_ * D_ + lane * 4;
    const float* pb = pre + b * L_;

    float4 hA0, hA1, hA2, hA3, wA0, wA1, wA2, wA3;
    float4 hB0, hB1, hB2, hB3, wB0, wB1, wB2, wB3;
    float preA, preB;

#define LOADROW(row, H0,H1,H2,H3, W0,W1,W2,W3, PV) do { \
    const float* ph_ = sb + (size_t)(row) * D_; \
    const float* pw_ = wb + (size_t)(row) * D_; \
    H0 = *(const float4*)(ph_);       W0 = *(const float4*)(pw_); \
    H1 = *(const float4*)(ph_ + 256); W1 = *(const float4*)(pw_ + 256); \
    H2 = *(const float4*)(ph_ + 512); W2 = *(const float4*)(pw_ + 512); \
    H3 = *(const float4*)(ph_ + 768); W3 = *(const float4*)(pw_ + 768); \
    PV = pb[(row)]; \
} while (0)

#define DOT4(acc_, X, Y) do { \
    acc_ = fmaf((X).x, (Y).x, acc_); acc_ = fmaf((X).y, (Y).y, acc_); \
    acc_ = fmaf((X).z, (Y).z, acc_); acc_ = fmaf((X).w, (Y).w, acc_); \
} while (0)

#define STEP(t, H0,H1,H2,H3, W0,W1,W2,W3, PV) do { \
    float4 t0_, t1_, t2_, t3_; \
    t0_.x = fast_tanh(s0.x); t0_.y = fast_tanh(s0.y); t0_.z = fast_tanh(s0.z); t0_.w = fast_tanh(s0.w); \
    t1_.x = fast_tanh(s1.x); t1_.y = fast_tanh(s1.y); t1_.z = fast_tanh(s1.z); t1_.w = fast_tanh(s1.w); \
    t2_.x = fast_tanh(s2.x); t2_.y = fast_tanh(s2.y); t2_.z = fast_tanh(s2.z); t2_.w = fast_tanh(s2.w); \
    t3_.x = fast_tanh(s3.x); t3_.y = fast_tanh(s3.y); t3_.z = fast_tanh(s3.z); t3_.w = fast_tanh(s3.w); \
    float r1_ = 0.f; \
    DOT4(r1_, W0, t0_); DOT4(r1_, W1, t1_); DOT4(r1_, W2, t2_); DOT4(r1_, W3, t3_); \
    _Pragma("unroll") \
    for (int off_ = 32; off_; off_ >>= 1) r1_ += __shfl_xor(r1_, off_); \
    float prob_ = fast_sigmoid((PV) - r1_); \
    if (lane == 0) out[b * L_ + (t)] = prob_; \
    s0.x = fmaf(prob_, (H0).x, s0.x); s0.y = fmaf(prob_, (H0).y, s0.y); \
    s0.z = fmaf(prob_, (H0).z, s0.z); s0.w = fmaf(prob_, (H0).w, s0.w); \
    s1.x = fmaf(prob_, (H1).x, s1.x); s1.y = fmaf(prob_, (H1).y, s1.y); \
    s1.z = fmaf(prob_, (H1).z, s1.z); s1.w = fmaf(prob_, (H1).w, s1.w); \
    s2.x = fmaf(prob_, (H2).x, s2.x); s2.y = fmaf(prob_, (H2).y, s2.y); \
    s2.z = fmaf(prob_, (H2).z, s2.z); s2.w = fmaf(prob_, (H2).w, s2.w); \
    s3.x = fmaf(prob_, (H3).x, s3.x); s3.y = fmaf(prob_, (H3).y, s3.y); \
    s3.z = fmaf(prob_, (H3).z, s3.z); s3.w = fmaf(prob_, (H3).w, s3.w); \
} while (0)

    LOADROW(0, hA0,hA1,hA2,hA3, wA0,wA1,wA2,wA3, preA);
    int t = 0;
    while (true) {
        int tn = min(t + 1, len - 1);
        LOADROW(tn, hB0,hB1,hB2,hB3, wB0,wB1,wB2,wB3, preB);
        STEP(t, hA0,hA1,hA2,hA3, wA0,wA1,wA2,wA3, preA);
        ++t; if (t >= len) break;
        tn = min(t + 1, len - 1);
        LOADROW(tn, hA0,hA1,hA2,hA3, wA0,wA1,wA2,wA3, preA);
        STEP(t, hB0,hB1,hB2,hB3, wB0,wB1,wB2,wB3, preB);
        ++t; if (t >= len) break;
    }
#undef LOADROW
#undef DOT4
#undef STEP
}

// ---------- launch ----------
extern "C" void kernel_launch(void* const* d_in, const int* in_sizes, int n_in,
                              void* d_out, int out_size, void* d_ws, size_t ws_size,
                              hipStream_t stream)
{
    const float* sent      = (const float*)d_in[0];
    const float* fc_w      = (const float*)d_in[1];
    const float* fc_b      = (const float*)d_in[2];
    const float* content_w = (const float*)d_in[3];
    const float* sal_w     = (const float*)d_in[4];
    const float* nov_w     = (const float*)d_in[5];
    const float* abs_emb   = (const float*)d_in[6];
    const float* rel_emb   = (const float*)d_in[7];
    const float* abs_w     = (const float*)d_in[8];
    const float* rel_w     = (const float*)d_in[9];
    const float* bias      = (const float*)d_in[10];
    const int*   doc_lens  = (const int*)d_in[11];
    float* out = (float*)d_out;

    char* ws = (char*)d_ws;
    const size_t MB = 1024 * 1024;
    _Float16* docs_hi = (_Float16*)(ws);             // 1 MiB
    _Float16* docs_lo = (_Float16*)(ws + 1 * MB);    // 1 MiB
    _Float16* dv_hi   = (_Float16*)(ws + 2 * MB);    // 1 MiB
    _Float16* dv_lo   = (_Float16*)(ws + 3 * MB);    // 1 MiB
    float*    u       = (float*)(ws + 4 * MB);       // 2 MiB
    float*    abs_p   = (float*)(ws + 6 * MB);
    float*    rel_vals= (float*)(ws + 6 * MB + 512);
    _Float16* fcw_hi  = (_Float16*)(ws + 7 * MB);    // 2 MiB
    _Float16* fcw_lo  = (_Float16*)(ws + 9 * MB);    // 2 MiB
    _Float16* salw_hi = (_Float16*)(ws + 11 * MB);   // 2 MiB
    _Float16* salw_lo = (_Float16*)(ws + 13 * MB);   // 2 MiB
    _Float16* Bt_hi   = (_Float16*)(ws + 15 * MB);   // 2 MiB
    _Float16* Bt_lo   = (_Float16*)(ws + 17 * MB);   // 2 MiB
    float*    pre     = (float*)(ws + 19 * MB);      // 200 KiB
    float*    hWn     = (float*)(ws + 20 * MB);      // 200 MiB

    // 1) docs masked mean + split
    docs_kernel<<<dim3(B_), 256, 0, stream>>>(sent, doc_lens, docs_hi, docs_lo);

    // 2) embedding dots
    emb_kernel<<<dim3(1), 128, 0, stream>>>(abs_emb, rel_emb, abs_w, rel_w, abs_p, rel_vals);

    // 3) split fc_w / sal_w (already [N,K] layout)
    wsplit_kernel<<<dim3(2 * D_ * D_ / (256 * 4)), 256, 0, stream>>>(
        fc_w, sal_w, fcw_hi, fcw_lo, salw_hi, salw_lo);

    // 4) transpose + split nov_w
    convert_b<<<dim3(32, 32), 256, 0, stream>>>(nov_w, Bt_hi, Bt_lo);

    // 5) doc_vec = tanh(docs @ fc_w^T + fc_b) -> f16 pair
    gemm_ms<1><<<dim3(D_ / 128, B_ / 128), 256, 0, stream>>>(
        docs_hi, docs_lo, fcw_hi, fcw_lo, fc_b, nullptr, dv_hi, dv_lo);

    // 6) u = doc_vec @ sal_w^T + content_w -> fp32
    gemm_ms<2><<<dim3(D_ / 128, B_ / 128), 256, 0, stream>>>(
        dv_hi, dv_lo, salw_hi, salw_lo, content_w, u, nullptr, nullptr);

    // 7) hWn = sent @ nov_w  + fused pre[b,t] (XCD-swizzled 1D grid)
    gemm_hWn<<<dim3(3200), 256, 0, stream>>>(
        sent, Bt_hi, Bt_lo, hWn, u, abs_p, rel_vals, bias, doc_lens, pre);

    // 8) scan: one wave per batch
    scan_kernel<<<dim3(B_), 64, 0, stream>>>(
        sent, hWn, pre, doc_lens, out);
}

// Round 7
// 625.114 us; speedup vs baseline: 1.5262x; 1.3017x over previous
//
#include <hip/hip_runtime.h>
#include <math.h>

#define B_ 512
#define L_ 100
#define D_ 1024
#define POS_DIM_ 50
#define GM 51200
#define GN 1024
#define GK 1024
#define LDT 40   // padded LDS row stride (halfwords) for A tiles in gemm_hWn

typedef _Float16 half8 __attribute__((ext_vector_type(8)));
typedef _Float16 half4 __attribute__((ext_vector_type(4)));
typedef float floatx4 __attribute__((ext_vector_type(4)));

// ---------- fast device math ----------
__device__ __forceinline__ float fast_tanh(float x) {
    float e = __expf(2.0f * x);
    return 1.0f - 2.0f * __builtin_amdgcn_rcpf(e + 1.0f);
}
__device__ __forceinline__ float fast_sigmoid(float x) {
    return __builtin_amdgcn_rcpf(1.0f + __expf(-x));
}

// async global->LDS, 16B per lane; lds base must be wave-uniform
__device__ __forceinline__ void gll16(const void* g, void* l) {
    __builtin_amdgcn_global_load_lds(
        (const __attribute__((address_space(1))) void*)g,
        (__attribute__((address_space(3))) void*)l, 16, 0, 0);
}

// ---------- Kernel 0: prefix sum of doc_lens (single wave) ----------
// prefix[b] = sum_{i<b} doc_lens[i]; prefix[512] = total compacted rows.
__global__ __launch_bounds__(64) void prefix_kernel(
    const int* __restrict__ dl, int* __restrict__ prefix)
{
    int lane = threadIdx.x;
    int4 a = ((const int4*)dl)[lane * 2];
    int4 b = ((const int4*)dl)[lane * 2 + 1];
    int v0 = a.x, v1 = a.y, v2 = a.z, v3 = a.w;
    int v4 = b.x, v5 = b.y, v6 = b.z, v7 = b.w;
    int local = v0 + v1 + v2 + v3 + v4 + v5 + v6 + v7;
    int inc = local;
    #pragma unroll
    for (int off = 1; off < 64; off <<= 1) {
        int t = __shfl_up(inc, off);
        if (lane >= off) inc += t;
    }
    int run = inc - local;   // exclusive prefix of this lane's chunk
    int o0 = run;            run += v0;
    int o1 = run;            run += v1;
    int o2 = run;            run += v2;
    int o3 = run;            run += v3;
    int o4 = run;            run += v4;
    int o5 = run;            run += v5;
    int o6 = run;            run += v6;
    int o7 = run;
    int base = lane * 8;
    prefix[base]     = o0; prefix[base + 1] = o1;
    prefix[base + 2] = o2; prefix[base + 3] = o3;
    prefix[base + 4] = o4; prefix[base + 5] = o5;
    prefix[base + 6] = o6; prefix[base + 7] = o7;
    if (lane == 63) prefix[512] = inc;   // total (inc of last lane = grand total)
}

// ---------- Kernel 1: docs (masked mean) + f16 hi/lo split of docs ----------
__global__ __launch_bounds__(256) void docs_kernel(
    const float* __restrict__ sent, const int* __restrict__ doc_lens,
    _Float16* __restrict__ docs_hi, _Float16* __restrict__ docs_lo)
{
    int b = blockIdx.x;
    int tid = threadIdx.x;
    int len = doc_lens[b];
    float inv = 1.0f / (float)len;
    const float* p = sent + (size_t)b * L_ * D_ + tid * 4;
    float4 acc = {0.f, 0.f, 0.f, 0.f};
    float4 acc2 = {0.f, 0.f, 0.f, 0.f};
    int l = 0;
    for (; l + 1 < len; l += 2) {
        float4 v0 = *(const float4*)(p + (size_t)l * D_);
        float4 v1 = *(const float4*)(p + (size_t)(l + 1) * D_);
        acc.x += v0.x; acc.y += v0.y; acc.z += v0.z; acc.w += v0.w;
        acc2.x += v1.x; acc2.y += v1.y; acc2.z += v1.z; acc2.w += v1.w;
    }
    if (l < len) {
        float4 v0 = *(const float4*)(p + (size_t)l * D_);
        acc.x += v0.x; acc.y += v0.y; acc.z += v0.z; acc.w += v0.w;
    }
    acc.x += acc2.x; acc.y += acc2.y; acc.z += acc2.z; acc.w += acc2.w;
    float a[4] = {acc.x * inv, acc.y * inv, acc.z * inv, acc.w * inv};
    half4 h, lo;
    #pragma unroll
    for (int i = 0; i < 4; ++i) {
        _Float16 hi = (_Float16)a[i];
        h[i] = hi;
        lo[i] = (_Float16)(a[i] - (float)hi);
    }
    *(half4*)(docs_hi + (size_t)b * D_ + tid * 4) = h;
    *(half4*)(docs_lo + (size_t)b * D_ + tid * 4) = lo;
}

// ---------- Kernel 2: tiny embedding dots ----------
__global__ void emb_kernel(const float* __restrict__ abs_emb,
                           const float* __restrict__ rel_emb,
                           const float* __restrict__ abs_w,
                           const float* __restrict__ rel_w,
                           float* __restrict__ abs_p, float* __restrict__ rel_vals)
{
    int t = threadIdx.x;
    if (t < L_) {
        float a = 0.f;
        for (int j = 0; j < POS_DIM_; ++j) a += abs_emb[t * POS_DIM_ + j] * abs_w[j];
        abs_p[t] = a;
    }
    if (t < 10) {
        float r = 0.f;
        for (int j = 0; j < POS_DIM_; ++j) r += rel_emb[t * POS_DIM_ + j] * rel_w[j];
        rel_vals[t] = r;
    }
}

// ---------- Kernel 3: elementwise f16 hi/lo split of fc_w and sal_w ----------
__global__ __launch_bounds__(256) void wsplit_kernel(
    const float* __restrict__ fc_w, const float* __restrict__ sal_w,
    _Float16* __restrict__ fcw_hi, _Float16* __restrict__ fcw_lo,
    _Float16* __restrict__ salw_hi, _Float16* __restrict__ salw_lo)
{
    int id = blockIdx.x * 256 + threadIdx.x;
    int base = id * 4;
    const int NN = D_ * D_;
    const float* src; _Float16* dh; _Float16* dl; int off;
    if (base < NN) { src = fc_w; dh = fcw_hi; dl = fcw_lo; off = base; }
    else           { src = sal_w; dh = salw_hi; dl = salw_lo; off = base - NN; }
    float4 v = *(const float4*)(src + off);
    float a[4] = {v.x, v.y, v.z, v.w};
    half4 h, lo;
    #pragma unroll
    for (int i = 0; i < 4; ++i) {
        _Float16 hi = (_Float16)a[i];
        h[i] = hi;
        lo[i] = (_Float16)(a[i] - (float)hi);
    }
    *(half4*)(dh + off) = h;
    *(half4*)(dl + off) = lo;
}

// ---------- Kernel 4: transpose + f16 hi/lo split of nov_w ----------
__global__ __launch_bounds__(256) void convert_b(
    const float* __restrict__ B, _Float16* __restrict__ Bt_hi,
    _Float16* __restrict__ Bt_lo)
{
    __shared__ float ld[32][33];
    int k0 = blockIdx.x * 32, n0 = blockIdx.y * 32;
    int r  = threadIdx.x >> 3;
    int c4 = (threadIdx.x & 7) * 4;
    float4 v = *(const float4*)(B + (size_t)(k0 + r) * D_ + n0 + c4);
    ld[r][c4] = v.x; ld[r][c4 + 1] = v.y; ld[r][c4 + 2] = v.z; ld[r][c4 + 3] = v.w;
    __syncthreads();
    half4 h, l;
    #pragma unroll
    for (int i = 0; i < 4; ++i) {
        float x = ld[c4 + i][r];
        _Float16 hi = (_Float16)x;
        h[i] = hi;
        l[i] = (_Float16)(x - (float)hi);
    }
    *(half4*)(Bt_hi + (size_t)(n0 + r) * D_ + k0 + c4) = h;
    *(half4*)(Bt_lo + (size_t)(n0 + r) * D_ + k0 + c4) = l;
}

// ---------- Kernel 5: MFMA 3-pass f16-split GEMM for small GEMMs ----------
// A (hi/lo) [M,K] f16, B (hi/lo) [N,K] f16; all staging via global_load_lds.
// EPI 1: v = tanh(acc+X[n]) -> write f16 hi/lo pair (Oh, Ol)
// EPI 2: v = acc+X[n]       -> write fp32 O
template<int EPI>
__global__ __launch_bounds__(256, 2) void gemm_ms(
    const _Float16* __restrict__ Ah, const _Float16* __restrict__ Al,
    const _Float16* __restrict__ Bh, const _Float16* __restrict__ Bl,
    const float* __restrict__ X, float* __restrict__ O,
    _Float16* __restrict__ Oh, _Float16* __restrict__ Ol)
{
    __shared__ _Float16 sAh[128 * 32];
    __shared__ _Float16 sAl[128 * 32];
    __shared__ _Float16 sBh[128 * 32];
    __shared__ _Float16 sBl[128 * 32];

    int tid = threadIdx.x;
    int wave = tid >> 6, lane = tid & 63;
    int n0 = blockIdx.x * 128, m0 = blockIdx.y * 128;
    int wm = (wave >> 1) * 64, wn = (wave & 1) * 64;
    int tm = lane & 15, quad = lane >> 4;

    floatx4 acc[4][4];
    #pragma unroll
    for (int i = 0; i < 4; ++i)
        #pragma unroll
        for (int j = 0; j < 4; ++j)
            acc[i][j] = (floatx4){0.f, 0.f, 0.f, 0.f};

    int grow = lane >> 2;          // 0..15
    int gcol = (lane & 3) * 8;     // halfword offset
    const _Float16* pAh = Ah + (size_t)(m0 + wave * 32 + grow) * GK + gcol;
    const _Float16* pAl = Al + (size_t)(m0 + wave * 32 + grow) * GK + gcol;
    const _Float16* pBh = Bh + (size_t)(n0 + wave * 32 + grow) * GK + gcol;
    const _Float16* pBl = Bl + (size_t)(n0 + wave * 32 + grow) * GK + gcol;
    _Float16* lAh = sAh + wave * 32 * 32;
    _Float16* lAl = sAl + wave * 32 * 32;
    _Float16* lBh = sBh + wave * 32 * 32;
    _Float16* lBl = sBl + wave * 32 * 32;

    #pragma unroll 1
    for (int k0 = 0; k0 < GK; k0 += 32) {
        __syncthreads();   // previous iteration's fragment reads complete
        gll16(pAh + k0, lAh);
        gll16(pAh + 16 * GK + k0, lAh + 16 * 32);
        gll16(pAl + k0, lAl);
        gll16(pAl + 16 * GK + k0, lAl + 16 * 32);
        gll16(pBh + k0, lBh);
        gll16(pBh + 16 * GK + k0, lBh + 16 * 32);
        gll16(pBl + k0, lBl);
        gll16(pBl + 16 * GK + k0, lBl + 16 * 32);
        __syncthreads();   // drains vmcnt(0): LDS tile ready

        half8 fah[4], fal[4], fbh[4], fbl[4];
        #pragma unroll
        for (int mt = 0; mt < 4; ++mt) {
            int base = (wm + mt * 16 + tm) * 32 + quad * 8;
            fah[mt] = *(const half8*)(sAh + base);
            fal[mt] = *(const half8*)(sAl + base);
        }
        #pragma unroll
        for (int nt = 0; nt < 4; ++nt) {
            int base = (wn + nt * 16 + tm) * 32 + quad * 8;
            fbh[nt] = *(const half8*)(sBh + base);
            fbl[nt] = *(const half8*)(sBl + base);
        }
        #pragma unroll
        for (int mt = 0; mt < 4; ++mt)
            #pragma unroll
            for (int nt = 0; nt < 4; ++nt) {
                acc[mt][nt] = __builtin_amdgcn_mfma_f32_16x16x32_f16(
                    fah[mt], fbh[nt], acc[mt][nt], 0, 0, 0);
                acc[mt][nt] = __builtin_amdgcn_mfma_f32_16x16x32_f16(
                    fah[mt], fbl[nt], acc[mt][nt], 0, 0, 0);
                acc[mt][nt] = __builtin_amdgcn_mfma_f32_16x16x32_f16(
                    fal[mt], fbh[nt], acc[mt][nt], 0, 0, 0);
            }
    }

    #pragma unroll
    for (int mt = 0; mt < 4; ++mt) {
        #pragma unroll
        for (int nt = 0; nt < 4; ++nt) {
            int col = n0 + wn + nt * 16 + tm;
            int rowb = m0 + wm + mt * 16 + quad * 4;
            float xv = X[col];
            #pragma unroll
            for (int r = 0; r < 4; ++r) {
                float v = acc[mt][nt][r];
                if (EPI == 1) {
                    v = tanhf(v + xv);
                    _Float16 hi = (_Float16)v;
                    Oh[(size_t)(rowb + r) * GN + col] = hi;
                    Ol[(size_t)(rowb + r) * GN + col] = (_Float16)(v - (float)hi);
                } else {
                    O[(size_t)(rowb + r) * GN + col] = v + xv;
                }
            }
        }
    }
}

// ---------- Kernel 6: MFMA f16-split GEMM: hWn = sent @ nov_w (COMPACTED) ----------
// EXACT round-2 K-loop schedule (333 us known-good; r3-r6 variants all
// regressed — schedule frozen). Change is M-space only: rows are COMPACTED
// over valid (b, t<len) pairs via prefix[]; padding rows (~45%) are skipped.
// Blocks with m0 >= total early-exit (block-uniform). Per staging thread a
// one-time binary search maps compacted row -> (b,t); registers die before
// the loop so VGPR stays at the r2 level. C is written compacted.
__global__ __launch_bounds__(256, 2) void gemm_hWn(
    const float* __restrict__ A, const _Float16* __restrict__ Bt_hi,
    const _Float16* __restrict__ Bt_lo, float* __restrict__ C,
    const int* __restrict__ prefix)
{
    __shared__ _Float16 As_hi[128 * LDT];
    __shared__ _Float16 As_lo[128 * LDT];
    __shared__ _Float16 Bs_hi[128 * 32];
    __shared__ _Float16 Bs_lo[128 * 32];

    int tid  = threadIdx.x;
    int wave = tid >> 6, lane = tid & 63;
    int d = blockIdx.x;
    int islab = d & 7, nblk = (d >> 3) & 7, g = d >> 6;
    int m0 = (g * 8 + islab) * 128;
    int n0 = nblk * 128;

    int total = prefix[512];
    if (m0 >= total) return;        // block-uniform: no barrier divergence

    int wm = (wave >> 1) * 64, wn = (wave & 1) * 64;
    int tm   = lane & 15;
    int quad = lane >> 4;

    floatx4 acc[4][4];
    #pragma unroll
    for (int i = 0; i < 4; ++i)
        #pragma unroll
        for (int j = 0; j < 4; ++j)
            acc[i][j] = (floatx4){0.f, 0.f, 0.f, 0.f};

    // A staging: thread covers (compacted row, 16-elem k-half).
    // Map compacted row -> (b, t) once via binary search on prefix.
    int sr = tid >> 1;
    int sh = tid & 1;
    const float* Ap;
    {
        int r = m0 + sr;
        if (r > total - 1) r = total - 1;      // boundary tile clamp (rows unused)
        int lo = 0, hi = 512;
        while (hi - lo > 1) {
            int mid = (lo + hi) >> 1;
            if (prefix[mid] <= r) lo = mid; else hi = mid;
        }
        int t = r - prefix[lo];
        Ap = A + (size_t)(lo * L_ + t) * GK + sh * 16;
    }
    int sbase = sr * LDT + sh * 16;

    // B staging via gll: wave covers rows [wave*32, wave*32+32)
    int grow = lane >> 2;
    int gswz = ((lane & 3) ^ ((lane >> 3) & 3)) * 8;   // halfword offset
    const _Float16* pBh = Bt_hi + (size_t)(n0 + wave * 32 + grow) * GK + gswz;
    const _Float16* pBl = Bt_lo + (size_t)(n0 + wave * 32 + grow) * GK + gswz;
    _Float16* lBh = Bs_hi + wave * 32 * 32;
    _Float16* lBl = Bs_lo + wave * 32 * 32;

    #pragma unroll 1
    for (int k0 = 0; k0 < GK; k0 += 32) {
        float4 a0 = *(const float4*)(Ap + k0);
        float4 a1 = *(const float4*)(Ap + k0 + 4);
        float4 a2 = *(const float4*)(Ap + k0 + 8);
        float4 a3 = *(const float4*)(Ap + k0 + 12);

        half8 ah0, ah1, al0, al1;
        float af[16] = {a0.x, a0.y, a0.z, a0.w, a1.x, a1.y, a1.z, a1.w,
                        a2.x, a2.y, a2.z, a2.w, a3.x, a3.y, a3.z, a3.w};
        #pragma unroll
        for (int i = 0; i < 8; ++i) {
            _Float16 h = (_Float16)af[i];
            ah0[i] = h;
            al0[i] = (_Float16)(af[i] - (float)h);
        }
        #pragma unroll
        for (int i = 0; i < 8; ++i) {
            _Float16 h = (_Float16)af[8 + i];
            ah1[i] = h;
            al1[i] = (_Float16)(af[8 + i] - (float)h);
        }

        __syncthreads();   // previous iteration's fragment reads complete
        // B DMA into LDS (linear dest; source chunk pre-swizzled)
        gll16(pBh + k0, lBh);
        gll16(pBh + 16 * GK + k0, lBh + 16 * 32);
        gll16(pBl + k0, lBl);
        gll16(pBl + 16 * GK + k0, lBl + 16 * 32);
        // A stores
        *(half8*)(As_hi + sbase)     = ah0;
        *(half8*)(As_hi + sbase + 8) = ah1;
        *(half8*)(As_lo + sbase)     = al0;
        *(half8*)(As_lo + sbase + 8) = al1;
        __syncthreads();   // drains vmcnt (gll) + lgkm (stores)

        half8 fa_hi[4], fa_lo[4], fb_hi[4], fb_lo[4];
        #pragma unroll
        for (int mt = 0; mt < 4; ++mt) {
            int row = (wm + mt * 16 + tm) * LDT + quad * 8;
            fa_hi[mt] = *(const half8*)(As_hi + row);
            fa_lo[mt] = *(const half8*)(As_lo + row);
        }
        #pragma unroll
        for (int nt = 0; nt < 4; ++nt) {
            int row = wn + nt * 16 + tm;
            int rbase = row * 32 + ((quad ^ ((row >> 1) & 3)) << 3);
            fb_hi[nt] = *(const half8*)(Bs_hi + rbase);
            fb_lo[nt] = *(const half8*)(Bs_lo + rbase);
        }
        #pragma unroll
        for (int mt = 0; mt < 4; ++mt)
            #pragma unroll
            for (int nt = 0; nt < 4; ++nt) {
                acc[mt][nt] = __builtin_amdgcn_mfma_f32_16x16x32_f16(
                    fa_hi[mt], fb_hi[nt], acc[mt][nt], 0, 0, 0);
                acc[mt][nt] = __builtin_amdgcn_mfma_f32_16x16x32_f16(
                    fa_hi[mt], fb_lo[nt], acc[mt][nt], 0, 0, 0);
                acc[mt][nt] = __builtin_amdgcn_mfma_f32_16x16x32_f16(
                    fa_lo[mt], fb_hi[nt], acc[mt][nt], 0, 0, 0);
            }
    }

    #pragma unroll
    for (int mt = 0; mt < 4; ++mt) {
        #pragma unroll
        for (int nt = 0; nt < 4; ++nt) {
            int col = n0 + wn + nt * 16 + tm;
            int rowb = m0 + wm + mt * 16 + quad * 4;
            #pragma unroll
            for (int r = 0; r < 4; ++r)
                C[(size_t)(rowb + r) * GN + col] = acc[mt][nt][r];
        }
    }
}

// ---------- Kernel 7: scan — one wave per batch, all-register ----------
// r2-proven body; hWn is now COMPACTED, rows of doc b start at prefix[b].
__global__ __launch_bounds__(64) void scan_kernel(
    const float* __restrict__ sent, const float* __restrict__ hWn,
    const float* __restrict__ u, const float* __restrict__ abs_p,
    const float* __restrict__ rel_vals, const float* __restrict__ bias,
    const int* __restrict__ doc_lens, const int* __restrict__ prefix,
    float* __restrict__ out)
{
    int b = blockIdx.x;
    int lane = threadIdx.x;
    int len = doc_lens[b];
    float lenf = (float)len;

    for (int l = len + lane; l < L_; l += 64) out[b * L_ + l] = 0.f;

    // lane owns cols {lane*4 + j*256 : j=0..3, +0..3}
    const float* ub = u + (size_t)b * D_ + lane * 4;
    float4 ur0 = *(const float4*)(ub);
    float4 ur1 = *(const float4*)(ub + 256);
    float4 ur2 = *(const float4*)(ub + 512);
    float4 ur3 = *(const float4*)(ub + 768);

    float4 s0 = {0.f,0.f,0.f,0.f}, s1 = {0.f,0.f,0.f,0.f};
    float4 s2 = {0.f,0.f,0.f,0.f}, s3 = {0.f,0.f,0.f,0.f};

    const float* sb = sent + (size_t)b * L_ * D_ + lane * 4;
    const float* wb = hWn  + (size_t)prefix[b] * D_ + lane * 4;   // compacted
    float biasv = bias[0];

    float4 hA0, hA1, hA2, hA3, wA0, wA1, wA2, wA3;
    float4 hB0, hB1, hB2, hB3, wB0, wB1, wB2, wB3;

#define LOADROW(row, H0,H1,H2,H3, W0,W1,W2,W3) do { \
    const float* ph_ = sb + (size_t)(row) * D_; \
    const float* pw_ = wb + (size_t)(row) * D_; \
    H0 = *(const float4*)(ph_);       W0 = *(const float4*)(pw_); \
    H1 = *(const float4*)(ph_ + 256); W1 = *(const float4*)(pw_ + 256); \
    H2 = *(const float4*)(ph_ + 512); W2 = *(const float4*)(pw_ + 512); \
    H3 = *(const float4*)(ph_ + 768); W3 = *(const float4*)(pw_ + 768); \
} while (0)

#define DOT4(acc_, X, Y) do { \
    acc_ = fmaf((X).x, (Y).x, acc_); acc_ = fmaf((X).y, (Y).y, acc_); \
    acc_ = fmaf((X).z, (Y).z, acc_); acc_ = fmaf((X).w, (Y).w, acc_); \
} while (0)

#define STEP(t, H0,H1,H2,H3, W0,W1,W2,W3) do { \
    float4 t0_, t1_, t2_, t3_; \
    t0_.x = fast_tanh(s0.x); t0_.y = fast_tanh(s0.y); t0_.z = fast_tanh(s0.z); t0_.w = fast_tanh(s0.w); \
    t1_.x = fast_tanh(s1.x); t1_.y = fast_tanh(s1.y); t1_.z = fast_tanh(s1.z); t1_.w = fast_tanh(s1.w); \
    t2_.x = fast_tanh(s2.x); t2_.y = fast_tanh(s2.y); t2_.z = fast_tanh(s2.z); t2_.w = fast_tanh(s2.w); \
    t3_.x = fast_tanh(s3.x); t3_.y = fast_tanh(s3.y); t3_.z = fast_tanh(s3.z); t3_.w = fast_tanh(s3.w); \
    float r1_ = 0.f, r2_ = 0.f; \
    DOT4(r1_, W0, t0_); DOT4(r1_, W1, t1_); DOT4(r1_, W2, t2_); DOT4(r1_, W3, t3_); \
    DOT4(r2_, H0, ur0); DOT4(r2_, H1, ur1); DOT4(r2_, H2, ur2); DOT4(r2_, H3, ur3); \
    _Pragma("unroll") \
    for (int off_ = 32; off_; off_ >>= 1) { \
        r1_ += __shfl_xor(r1_, off_); \
        r2_ += __shfl_xor(r2_, off_); \
    } \
    int ridx_ = (int)rintf((float)((t) + 1) * 9.0f / lenf); \
    ridx_ = min(max(ridx_, 0), 9); \
    float pre_ = r2_ + abs_p[(t)] + rel_vals[ridx_] + biasv - r1_; \
    float prob_ = fast_sigmoid(pre_); \
    if (lane == 0) out[b * L_ + (t)] = prob_; \
    s0.x = fmaf(prob_, (H0).x, s0.x); s0.y = fmaf(prob_, (H0).y, s0.y); \
    s0.z = fmaf(prob_, (H0).z, s0.z); s0.w = fmaf(prob_, (H0).w, s0.w); \
    s1.x = fmaf(prob_, (H1).x, s1.x); s1.y = fmaf(prob_, (H1).y, s1.y); \
    s1.z = fmaf(prob_, (H1).z, s1.z); s1.w = fmaf(prob_, (H1).w, s1.w); \
    s2.x = fmaf(prob_, (H2).x, s2.x); s2.y = fmaf(prob_, (H2).y, s2.y); \
    s2.z = fmaf(prob_, (H2).z, s2.z); s2.w = fmaf(prob_, (H2).w, s2.w); \
    s3.x = fmaf(prob_, (H3).x, s3.x); s3.y = fmaf(prob_, (H3).y, s3.y); \
    s3.z = fmaf(prob_, (H3).z, s3.z); s3.w = fmaf(prob_, (H3).w, s3.w); \
} while (0)

    LOADROW(0, hA0,hA1,hA2,hA3, wA0,wA1,wA2,wA3);
    int t = 0;
    while (true) {
        int tn = min(t + 1, len - 1);
        LOADROW(tn, hB0,hB1,hB2,hB3, wB0,wB1,wB2,wB3);
        STEP(t, hA0,hA1,hA2,hA3, wA0,wA1,wA2,wA3);
        ++t; if (t >= len) break;
        tn = min(t + 1, len - 1);
        LOADROW(tn, hA0,hA1,hA2,hA3, wA0,wA1,wA2,wA3);
        STEP(t, hB0,hB1,hB2,hB3, wB0,wB1,wB2,wB3);
        ++t; if (t >= len) break;
    }
#undef LOADROW
#undef DOT4
#undef STEP
}

// ---------- launch ----------
extern "C" void kernel_launch(void* const* d_in, const int* in_sizes, int n_in,
                              void* d_out, int out_size, void* d_ws, size_t ws_size,
                              hipStream_t stream)
{
    const float* sent      = (const float*)d_in[0];
    const float* fc_w      = (const float*)d_in[1];
    const float* fc_b      = (const float*)d_in[2];
    const float* content_w = (const float*)d_in[3];
    const float* sal_w     = (const float*)d_in[4];
    const float* nov_w     = (const float*)d_in[5];
    const float* abs_emb   = (const float*)d_in[6];
    const float* rel_emb   = (const float*)d_in[7];
    const float* abs_w     = (const float*)d_in[8];
    const float* rel_w     = (const float*)d_in[9];
    const float* bias      = (const float*)d_in[10];
    const int*   doc_lens  = (const int*)d_in[11];
    float* out = (float*)d_out;

    char* ws = (char*)d_ws;
    const size_t MB = 1024 * 1024;
    _Float16* docs_hi = (_Float16*)(ws);             // 1 MiB
    _Float16* docs_lo = (_Float16*)(ws + 1 * MB);    // 1 MiB
    _Float16* dv_hi   = (_Float16*)(ws + 2 * MB);    // 1 MiB
    _Float16* dv_lo   = (_Float16*)(ws + 3 * MB);    // 1 MiB
    float*    u       = (float*)(ws + 4 * MB);       // 2 MiB
    float*    abs_p   = (float*)(ws + 6 * MB);
    float*    rel_vals= (float*)(ws + 6 * MB + 512);
    _Float16* fcw_hi  = (_Float16*)(ws + 7 * MB);    // 2 MiB
    _Float16* fcw_lo  = (_Float16*)(ws + 9 * MB);    // 2 MiB
    _Float16* salw_hi = (_Float16*)(ws + 11 * MB);   // 2 MiB
    _Float16* salw_lo = (_Float16*)(ws + 13 * MB);   // 2 MiB
    _Float16* Bt_hi   = (_Float16*)(ws + 15 * MB);   // 2 MiB
    _Float16* Bt_lo   = (_Float16*)(ws + 17 * MB);   // 2 MiB
    int*      prefix  = (int*)(ws + 19 * MB);        // 513 ints
    float*    hWn     = (float*)(ws + 20 * MB);      // 200 MiB (compacted)

    // 0) prefix sums of doc_lens
    prefix_kernel<<<dim3(1), 64, 0, stream>>>(doc_lens, prefix);

    // 1) docs masked mean + split
    docs_kernel<<<dim3(B_), 256, 0, stream>>>(sent, doc_lens, docs_hi, docs_lo);

    // 2) embedding dots
    emb_kernel<<<dim3(1), 128, 0, stream>>>(abs_emb, rel_emb, abs_w, rel_w, abs_p, rel_vals);

    // 3) split fc_w / sal_w (already [N,K] layout)
    wsplit_kernel<<<dim3(2 * D_ * D_ / (256 * 4)), 256, 0, stream>>>(
        fc_w, sal_w, fcw_hi, fcw_lo, salw_hi, salw_lo);

    // 4) transpose + split nov_w
    convert_b<<<dim3(32, 32), 256, 0, stream>>>(nov_w, Bt_hi, Bt_lo);

    // 5) hWn = sent @ nov_w over COMPACTED rows (XCD-swizzled 1D grid)
    gemm_hWn<<<dim3(3200), 256, 0, stream>>>(sent, Bt_hi, Bt_lo, hWn, prefix);

    // 6) doc_vec = tanh(docs @ fc_w^T + fc_b) -> f16 pair
    gemm_ms<1><<<dim3(D_ / 128, B_ / 128), 256, 0, stream>>>(
        docs_hi, docs_lo, fcw_hi, fcw_lo, fc_b, nullptr, dv_hi, dv_lo);

    // 7) u = doc_vec @ sal_w^T + content_w -> fp32
    gemm_ms<2><<<dim3(D_ / 128, B_ / 128), 256, 0, stream>>>(
        dv_hi, dv_lo, salw_hi, salw_lo, content_w, u, nullptr, nullptr);

    // 8) scan: one wave per batch (compacted hWn base)
    scan_kernel<<<dim3(B_), 64, 0, stream>>>(
        sent, hWn, u, abs_p, rel_vals, bias, doc_lens, prefix, out);
}

// Round 8
// 622.189 us; speedup vs baseline: 1.5334x; 1.0047x over previous
//
#include <hip/hip_runtime.h>
#include <math.h>

#define B_ 512
#define L_ 100
#define D_ 1024
#define POS_DIM_ 50
#define GM 51200
#define GN 1024
#define GK 1024
#define LDT 40   // padded LDS row stride (halfwords) for A tiles in gemm_hWn

typedef _Float16 half8 __attribute__((ext_vector_type(8)));
typedef _Float16 half4 __attribute__((ext_vector_type(4)));
typedef float floatx4 __attribute__((ext_vector_type(4)));

// ---------- fast device math ----------
__device__ __forceinline__ float fast_tanh(float x) {
    float e = __expf(2.0f * x);
    return 1.0f - 2.0f * __builtin_amdgcn_rcpf(e + 1.0f);
}
__device__ __forceinline__ float fast_sigmoid(float x) {
    return __builtin_amdgcn_rcpf(1.0f + __expf(-x));
}

// async global->LDS, 16B per lane; lds base must be wave-uniform
__device__ __forceinline__ void gll16(const void* g, void* l) {
    __builtin_amdgcn_global_load_lds(
        (const __attribute__((address_space(1))) void*)g,
        (__attribute__((address_space(3))) void*)l, 16, 0, 0);
}

// ---------- Kernel 0: prefix sum of doc_lens (single wave) ----------
// prefix[b] = sum_{i<b} doc_lens[i]; prefix[512] = total compacted rows.
__global__ __launch_bounds__(64) void prefix_kernel(
    const int* __restrict__ dl, int* __restrict__ prefix)
{
    int lane = threadIdx.x;
    int4 a = ((const int4*)dl)[lane * 2];
    int4 b = ((const int4*)dl)[lane * 2 + 1];
    int v0 = a.x, v1 = a.y, v2 = a.z, v3 = a.w;
    int v4 = b.x, v5 = b.y, v6 = b.z, v7 = b.w;
    int local = v0 + v1 + v2 + v3 + v4 + v5 + v6 + v7;
    int inc = local;
    #pragma unroll
    for (int off = 1; off < 64; off <<= 1) {
        int t = __shfl_up(inc, off);
        if (lane >= off) inc += t;
    }
    int run = inc - local;   // exclusive prefix of this lane's chunk
    int o0 = run;            run += v0;
    int o1 = run;            run += v1;
    int o2 = run;            run += v2;
    int o3 = run;            run += v3;
    int o4 = run;            run += v4;
    int o5 = run;            run += v5;
    int o6 = run;            run += v6;
    int o7 = run;
    int base = lane * 8;
    prefix[base]     = o0; prefix[base + 1] = o1;
    prefix[base + 2] = o2; prefix[base + 3] = o3;
    prefix[base + 4] = o4; prefix[base + 5] = o5;
    prefix[base + 6] = o6; prefix[base + 7] = o7;
    if (lane == 63) prefix[512] = inc;   // total (inc of last lane = grand total)
}

// ---------- Kernel 1: docs (masked mean) + f16 hi/lo split of docs ----------
__global__ __launch_bounds__(256) void docs_kernel(
    const float* __restrict__ sent, const int* __restrict__ doc_lens,
    _Float16* __restrict__ docs_hi, _Float16* __restrict__ docs_lo)
{
    int b = blockIdx.x;
    int tid = threadIdx.x;
    int len = doc_lens[b];
    float inv = 1.0f / (float)len;
    const float* p = sent + (size_t)b * L_ * D_ + tid * 4;
    float4 acc = {0.f, 0.f, 0.f, 0.f};
    float4 acc2 = {0.f, 0.f, 0.f, 0.f};
    int l = 0;
    for (; l + 1 < len; l += 2) {
        float4 v0 = *(const float4*)(p + (size_t)l * D_);
        float4 v1 = *(const float4*)(p + (size_t)(l + 1) * D_);
        acc.x += v0.x; acc.y += v0.y; acc.z += v0.z; acc.w += v0.w;
        acc2.x += v1.x; acc2.y += v1.y; acc2.z += v1.z; acc2.w += v1.w;
    }
    if (l < len) {
        float4 v0 = *(const float4*)(p + (size_t)l * D_);
        acc.x += v0.x; acc.y += v0.y; acc.z += v0.z; acc.w += v0.w;
    }
    acc.x += acc2.x; acc.y += acc2.y; acc.z += acc2.z; acc.w += acc2.w;
    float a[4] = {acc.x * inv, acc.y * inv, acc.z * inv, acc.w * inv};
    half4 h, lo;
    #pragma unroll
    for (int i = 0; i < 4; ++i) {
        _Float16 hi = (_Float16)a[i];
        h[i] = hi;
        lo[i] = (_Float16)(a[i] - (float)hi);
    }
    *(half4*)(docs_hi + (size_t)b * D_ + tid * 4) = h;
    *(half4*)(docs_lo + (size_t)b * D_ + tid * 4) = lo;
}

// ---------- Kernel 2: tiny embedding dots ----------
__global__ void emb_kernel(const float* __restrict__ abs_emb,
                           const float* __restrict__ rel_emb,
                           const float* __restrict__ abs_w,
                           const float* __restrict__ rel_w,
                           float* __restrict__ abs_p, float* __restrict__ rel_vals)
{
    int t = threadIdx.x;
    if (t < L_) {
        float a = 0.f;
        for (int j = 0; j < POS_DIM_; ++j) a += abs_emb[t * POS_DIM_ + j] * abs_w[j];
        abs_p[t] = a;
    }
    if (t < 10) {
        float r = 0.f;
        for (int j = 0; j < POS_DIM_; ++j) r += rel_emb[t * POS_DIM_ + j] * rel_w[j];
        rel_vals[t] = r;
    }
}

// ---------- Kernel 3: elementwise f16 hi/lo split of fc_w and sal_w ----------
__global__ __launch_bounds__(256) void wsplit_kernel(
    const float* __restrict__ fc_w, const float* __restrict__ sal_w,
    _Float16* __restrict__ fcw_hi, _Float16* __restrict__ fcw_lo,
    _Float16* __restrict__ salw_hi, _Float16* __restrict__ salw_lo)
{
    int id = blockIdx.x * 256 + threadIdx.x;
    int base = id * 4;
    const int NN = D_ * D_;
    const float* src; _Float16* dh; _Float16* dl; int off;
    if (base < NN) { src = fc_w; dh = fcw_hi; dl = fcw_lo; off = base; }
    else           { src = sal_w; dh = salw_hi; dl = salw_lo; off = base - NN; }
    float4 v = *(const float4*)(src + off);
    float a[4] = {v.x, v.y, v.z, v.w};
    half4 h, lo;
    #pragma unroll
    for (int i = 0; i < 4; ++i) {
        _Float16 hi = (_Float16)a[i];
        h[i] = hi;
        lo[i] = (_Float16)(a[i] - (float)hi);
    }
    *(half4*)(dh + off) = h;
    *(half4*)(dl + off) = lo;
}

// ---------- Kernel 4: transpose + f16 hi/lo split of nov_w ----------
__global__ __launch_bounds__(256) void convert_b(
    const float* __restrict__ B, _Float16* __restrict__ Bt_hi,
    _Float16* __restrict__ Bt_lo)
{
    __shared__ float ld[32][33];
    int k0 = blockIdx.x * 32, n0 = blockIdx.y * 32;
    int r  = threadIdx.x >> 3;
    int c4 = (threadIdx.x & 7) * 4;
    float4 v = *(const float4*)(B + (size_t)(k0 + r) * D_ + n0 + c4);
    ld[r][c4] = v.x; ld[r][c4 + 1] = v.y; ld[r][c4 + 2] = v.z; ld[r][c4 + 3] = v.w;
    __syncthreads();
    half4 h, l;
    #pragma unroll
    for (int i = 0; i < 4; ++i) {
        float x = ld[c4 + i][r];
        _Float16 hi = (_Float16)x;
        h[i] = hi;
        l[i] = (_Float16)(x - (float)hi);
    }
    *(half4*)(Bt_hi + (size_t)(n0 + r) * D_ + k0 + c4) = h;
    *(half4*)(Bt_lo + (size_t)(n0 + r) * D_ + k0 + c4) = l;
}

// ---------- Kernel 5: MFMA 3-pass f16-split GEMM for small GEMMs ----------
// A (hi/lo) [M,K] f16, B (hi/lo) [N,K] f16; all staging via global_load_lds.
// EPI 1: v = tanh(acc+X[n]) -> write f16 hi/lo pair (Oh, Ol)
// EPI 2: v = acc+X[n]       -> write fp32 O
template<int EPI>
__global__ __launch_bounds__(256, 2) void gemm_ms(
    const _Float16* __restrict__ Ah, const _Float16* __restrict__ Al,
    const _Float16* __restrict__ Bh, const _Float16* __restrict__ Bl,
    const float* __restrict__ X, float* __restrict__ O,
    _Float16* __restrict__ Oh, _Float16* __restrict__ Ol)
{
    __shared__ _Float16 sAh[128 * 32];
    __shared__ _Float16 sAl[128 * 32];
    __shared__ _Float16 sBh[128 * 32];
    __shared__ _Float16 sBl[128 * 32];

    int tid = threadIdx.x;
    int wave = tid >> 6, lane = tid & 63;
    int n0 = blockIdx.x * 128, m0 = blockIdx.y * 128;
    int wm = (wave >> 1) * 64, wn = (wave & 1) * 64;
    int tm = lane & 15, quad = lane >> 4;

    floatx4 acc[4][4];
    #pragma unroll
    for (int i = 0; i < 4; ++i)
        #pragma unroll
        for (int j = 0; j < 4; ++j)
            acc[i][j] = (floatx4){0.f, 0.f, 0.f, 0.f};

    int grow = lane >> 2;          // 0..15
    int gcol = (lane & 3) * 8;     // halfword offset
    const _Float16* pAh = Ah + (size_t)(m0 + wave * 32 + grow) * GK + gcol;
    const _Float16* pAl = Al + (size_t)(m0 + wave * 32 + grow) * GK + gcol;
    const _Float16* pBh = Bh + (size_t)(n0 + wave * 32 + grow) * GK + gcol;
    const _Float16* pBl = Bl + (size_t)(n0 + wave * 32 + grow) * GK + gcol;
    _Float16* lAh = sAh + wave * 32 * 32;
    _Float16* lAl = sAl + wave * 32 * 32;
    _Float16* lBh = sBh + wave * 32 * 32;
    _Float16* lBl = sBl + wave * 32 * 32;

    #pragma unroll 1
    for (int k0 = 0; k0 < GK; k0 += 32) {
        __syncthreads();   // previous iteration's fragment reads complete
        gll16(pAh + k0, lAh);
        gll16(pAh + 16 * GK + k0, lAh + 16 * 32);
        gll16(pAl + k0, lAl);
        gll16(pAl + 16 * GK + k0, lAl + 16 * 32);
        gll16(pBh + k0, lBh);
        gll16(pBh + 16 * GK + k0, lBh + 16 * 32);
        gll16(pBl + k0, lBl);
        gll16(pBl + 16 * GK + k0, lBl + 16 * 32);
        __syncthreads();   // drains vmcnt(0): LDS tile ready

        half8 fah[4], fal[4], fbh[4], fbl[4];
        #pragma unroll
        for (int mt = 0; mt < 4; ++mt) {
            int base = (wm + mt * 16 + tm) * 32 + quad * 8;
            fah[mt] = *(const half8*)(sAh + base);
            fal[mt] = *(const half8*)(sAl + base);
        }
        #pragma unroll
        for (int nt = 0; nt < 4; ++nt) {
            int base = (wn + nt * 16 + tm) * 32 + quad * 8;
            fbh[nt] = *(const half8*)(sBh + base);
            fbl[nt] = *(const half8*)(sBl + base);
        }
        #pragma unroll
        for (int mt = 0; mt < 4; ++mt)
            #pragma unroll
            for (int nt = 0; nt < 4; ++nt) {
                acc[mt][nt] = __builtin_amdgcn_mfma_f32_16x16x32_f16(
                    fah[mt], fbh[nt], acc[mt][nt], 0, 0, 0);
                acc[mt][nt] = __builtin_amdgcn_mfma_f32_16x16x32_f16(
                    fah[mt], fbl[nt], acc[mt][nt], 0, 0, 0);
                acc[mt][nt] = __builtin_amdgcn_mfma_f32_16x16x32_f16(
                    fal[mt], fbh[nt], acc[mt][nt], 0, 0, 0);
            }
    }

    #pragma unroll
    for (int mt = 0; mt < 4; ++mt) {
        #pragma unroll
        for (int nt = 0; nt < 4; ++nt) {
            int col = n0 + wn + nt * 16 + tm;
            int rowb = m0 + wm + mt * 16 + quad * 4;
            float xv = X[col];
            #pragma unroll
            for (int r = 0; r < 4; ++r) {
                float v = acc[mt][nt][r];
                if (EPI == 1) {
                    v = tanhf(v + xv);
                    _Float16 hi = (_Float16)v;
                    Oh[(size_t)(rowb + r) * GN + col] = hi;
                    Ol[(size_t)(rowb + r) * GN + col] = (_Float16)(v - (float)hi);
                } else {
                    O[(size_t)(rowb + r) * GN + col] = v + xv;
                }
            }
        }
    }
}

// ---------- Kernel 6: MFMA f16-split GEMM: hWn = sent @ nov_w (COMPACTED) ----------
// EXACT round-2 K-loop schedule (frozen). M-space compacted over valid
// (b, t<len) rows via prefix[]; padding rows (~45%) skipped. (r7: 178 us)
__global__ __launch_bounds__(256, 2) void gemm_hWn(
    const float* __restrict__ A, const _Float16* __restrict__ Bt_hi,
    const _Float16* __restrict__ Bt_lo, float* __restrict__ C,
    const int* __restrict__ prefix)
{
    __shared__ _Float16 As_hi[128 * LDT];
    __shared__ _Float16 As_lo[128 * LDT];
    __shared__ _Float16 Bs_hi[128 * 32];
    __shared__ _Float16 Bs_lo[128 * 32];

    int tid  = threadIdx.x;
    int wave = tid >> 6, lane = tid & 63;
    int d = blockIdx.x;
    int islab = d & 7, nblk = (d >> 3) & 7, g = d >> 6;
    int m0 = (g * 8 + islab) * 128;
    int n0 = nblk * 128;

    int total = prefix[512];
    if (m0 >= total) return;        // block-uniform: no barrier divergence

    int wm = (wave >> 1) * 64, wn = (wave & 1) * 64;
    int tm   = lane & 15;
    int quad = lane >> 4;

    floatx4 acc[4][4];
    #pragma unroll
    for (int i = 0; i < 4; ++i)
        #pragma unroll
        for (int j = 0; j < 4; ++j)
            acc[i][j] = (floatx4){0.f, 0.f, 0.f, 0.f};

    // A staging: thread covers (compacted row, 16-elem k-half).
    int sr = tid >> 1;
    int sh = tid & 1;
    const float* Ap;
    {
        int r = m0 + sr;
        if (r > total - 1) r = total - 1;      // boundary tile clamp (rows unused)
        int lo = 0, hi = 512;
        while (hi - lo > 1) {
            int mid = (lo + hi) >> 1;
            if (prefix[mid] <= r) lo = mid; else hi = mid;
        }
        int t = r - prefix[lo];
        Ap = A + (size_t)(lo * L_ + t) * GK + sh * 16;
    }
    int sbase = sr * LDT + sh * 16;

    // B staging via gll: wave covers rows [wave*32, wave*32+32)
    int grow = lane >> 2;
    int gswz = ((lane & 3) ^ ((lane >> 3) & 3)) * 8;   // halfword offset
    const _Float16* pBh = Bt_hi + (size_t)(n0 + wave * 32 + grow) * GK + gswz;
    const _Float16* pBl = Bt_lo + (size_t)(n0 + wave * 32 + grow) * GK + gswz;
    _Float16* lBh = Bs_hi + wave * 32 * 32;
    _Float16* lBl = Bs_lo + wave * 32 * 32;

    #pragma unroll 1
    for (int k0 = 0; k0 < GK; k0 += 32) {
        float4 a0 = *(const float4*)(Ap + k0);
        float4 a1 = *(const float4*)(Ap + k0 + 4);
        float4 a2 = *(const float4*)(Ap + k0 + 8);
        float4 a3 = *(const float4*)(Ap + k0 + 12);

        half8 ah0, ah1, al0, al1;
        float af[16] = {a0.x, a0.y, a0.z, a0.w, a1.x, a1.y, a1.z, a1.w,
                        a2.x, a2.y, a2.z, a2.w, a3.x, a3.y, a3.z, a3.w};
        #pragma unroll
        for (int i = 0; i < 8; ++i) {
            _Float16 h = (_Float16)af[i];
            ah0[i] = h;
            al0[i] = (_Float16)(af[i] - (float)h);
        }
        #pragma unroll
        for (int i = 0; i < 8; ++i) {
            _Float16 h = (_Float16)af[8 + i];
            ah1[i] = h;
            al1[i] = (_Float16)(af[8 + i] - (float)h);
        }

        __syncthreads();   // previous iteration's fragment reads complete
        // B DMA into LDS (linear dest; source chunk pre-swizzled)
        gll16(pBh + k0, lBh);
        gll16(pBh + 16 * GK + k0, lBh + 16 * 32);
        gll16(pBl + k0, lBl);
        gll16(pBl + 16 * GK + k0, lBl + 16 * 32);
        // A stores
        *(half8*)(As_hi + sbase)     = ah0;
        *(half8*)(As_hi + sbase + 8) = ah1;
        *(half8*)(As_lo + sbase)     = al0;
        *(half8*)(As_lo + sbase + 8) = al1;
        __syncthreads();   // drains vmcnt (gll) + lgkm (stores)

        half8 fa_hi[4], fa_lo[4], fb_hi[4], fb_lo[4];
        #pragma unroll
        for (int mt = 0; mt < 4; ++mt) {
            int row = (wm + mt * 16 + tm) * LDT + quad * 8;
            fa_hi[mt] = *(const half8*)(As_hi + row);
            fa_lo[mt] = *(const half8*)(As_lo + row);
        }
        #pragma unroll
        for (int nt = 0; nt < 4; ++nt) {
            int row = wn + nt * 16 + tm;
            int rbase = row * 32 + ((quad ^ ((row >> 1) & 3)) << 3);
            fb_hi[nt] = *(const half8*)(Bs_hi + rbase);
            fb_lo[nt] = *(const half8*)(Bs_lo + rbase);
        }
        #pragma unroll
        for (int mt = 0; mt < 4; ++mt)
            #pragma unroll
            for (int nt = 0; nt < 4; ++nt) {
                acc[mt][nt] = __builtin_amdgcn_mfma_f32_16x16x32_f16(
                    fa_hi[mt], fb_hi[nt], acc[mt][nt], 0, 0, 0);
                acc[mt][nt] = __builtin_amdgcn_mfma_f32_16x16x32_f16(
                    fa_hi[mt], fb_lo[nt], acc[mt][nt], 0, 0, 0);
                acc[mt][nt] = __builtin_amdgcn_mfma_f32_16x16x32_f16(
                    fa_lo[mt], fb_hi[nt], acc[mt][nt], 0, 0, 0);
            }
    }

    #pragma unroll
    for (int mt = 0; mt < 4; ++mt) {
        #pragma unroll
        for (int nt = 0; nt < 4; ++nt) {
            int col = n0 + wn + nt * 16 + tm;
            int rowb = m0 + wm + mt * 16 + quad * 4;
            #pragma unroll
            for (int r = 0; r < 4; ++r)
                C[(size_t)(rowb + r) * GN + col] = acc[mt][nt][r];
        }
    }
}

// ---------- Kernel 7: scan — one wave per batch, all-register ----------
// Critical-path optimized vs r7:
//  * single combined butterfly: reduce(r2) - reduce(r1) = reduce(r2 - r1)
//    -> 6 shfls/step instead of 12 (linearity of the wave reduction)
//  * 4-way ILP dot accumulators (chain depth ~4 fma instead of 16)
//  * depth-2 row prefetch (3 named register sets A/B/C; 1 wave/block, no
//    occupancy cost) to cover L2/HBM latency.
// Named registers only (rule #20). hWn compacted via prefix[b].
__global__ __launch_bounds__(64) void scan_kernel(
    const float* __restrict__ sent, const float* __restrict__ hWn,
    const float* __restrict__ u, const float* __restrict__ abs_p,
    const float* __restrict__ rel_vals, const float* __restrict__ bias,
    const int* __restrict__ doc_lens, const int* __restrict__ prefix,
    float* __restrict__ out)
{
    int b = blockIdx.x;
    int lane = threadIdx.x;
    int len = doc_lens[b];
    float lenf = (float)len;

    for (int l = len + lane; l < L_; l += 64) out[b * L_ + l] = 0.f;

    // lane owns cols {lane*4 + j*256 : j=0..3, +0..3}
    const float* ub = u + (size_t)b * D_ + lane * 4;
    float4 ur0 = *(const float4*)(ub);
    float4 ur1 = *(const float4*)(ub + 256);
    float4 ur2 = *(const float4*)(ub + 512);
    float4 ur3 = *(const float4*)(ub + 768);

    float4 s0 = {0.f,0.f,0.f,0.f}, s1 = {0.f,0.f,0.f,0.f};
    float4 s2 = {0.f,0.f,0.f,0.f}, s3 = {0.f,0.f,0.f,0.f};

    const float* sb = sent + (size_t)b * L_ * D_ + lane * 4;
    const float* wb = hWn  + (size_t)prefix[b] * D_ + lane * 4;   // compacted
    float biasv = bias[0];

    float4 hA0, hA1, hA2, hA3, wA0, wA1, wA2, wA3;
    float4 hB0, hB1, hB2, hB3, wB0, wB1, wB2, wB3;
    float4 hC0, hC1, hC2, hC3, wC0, wC1, wC2, wC3;

#define LOADROW(row, H0,H1,H2,H3, W0,W1,W2,W3) do { \
    const float* ph_ = sb + (size_t)(row) * D_; \
    const float* pw_ = wb + (size_t)(row) * D_; \
    H0 = *(const float4*)(ph_);       W0 = *(const float4*)(pw_); \
    H1 = *(const float4*)(ph_ + 256); W1 = *(const float4*)(pw_ + 256); \
    H2 = *(const float4*)(ph_ + 512); W2 = *(const float4*)(pw_ + 512); \
    H3 = *(const float4*)(ph_ + 768); W3 = *(const float4*)(pw_ + 768); \
} while (0)

#define DOT4(acc_, X, Y) do { \
    acc_ = fmaf((X).x, (Y).x, acc_); acc_ = fmaf((X).y, (Y).y, acc_); \
    acc_ = fmaf((X).z, (Y).z, acc_); acc_ = fmaf((X).w, (Y).w, acc_); \
} while (0)

#define STEP(t, H0,H1,H2,H3, W0,W1,W2,W3) do { \
    float4 t0_, t1_, t2_, t3_; \
    t0_.x = fast_tanh(s0.x); t0_.y = fast_tanh(s0.y); t0_.z = fast_tanh(s0.z); t0_.w = fast_tanh(s0.w); \
    t1_.x = fast_tanh(s1.x); t1_.y = fast_tanh(s1.y); t1_.z = fast_tanh(s1.z); t1_.w = fast_tanh(s1.w); \
    t2_.x = fast_tanh(s2.x); t2_.y = fast_tanh(s2.y); t2_.z = fast_tanh(s2.z); t2_.w = fast_tanh(s2.w); \
    t3_.x = fast_tanh(s3.x); t3_.y = fast_tanh(s3.y); t3_.z = fast_tanh(s3.z); t3_.w = fast_tanh(s3.w); \
    float p0_ = 0.f, p1_ = 0.f, p2_ = 0.f, p3_ = 0.f; \
    float q0_ = 0.f, q1_ = 0.f, q2_ = 0.f, q3_ = 0.f; \
    DOT4(p0_, W0, t0_); DOT4(p1_, W1, t1_); DOT4(p2_, W2, t2_); DOT4(p3_, W3, t3_); \
    DOT4(q0_, H0, ur0); DOT4(q1_, H1, ur1); DOT4(q2_, H2, ur2); DOT4(q3_, H3, ur3); \
    float d_ = ((q0_ + q1_) + (q2_ + q3_)) - ((p0_ + p1_) + (p2_ + p3_)); \
    _Pragma("unroll") \
    for (int off_ = 32; off_; off_ >>= 1) d_ += __shfl_xor(d_, off_); \
    int ridx_ = (int)rintf((float)((t) + 1) * 9.0f / lenf); \
    ridx_ = min(max(ridx_, 0), 9); \
    float pre_ = d_ + abs_p[(t)] + rel_vals[ridx_] + biasv; \
    float prob_ = fast_sigmoid(pre_); \
    if (lane == 0) out[b * L_ + (t)] = prob_; \
    s0.x = fmaf(prob_, (H0).x, s0.x); s0.y = fmaf(prob_, (H0).y, s0.y); \
    s0.z = fmaf(prob_, (H0).z, s0.z); s0.w = fmaf(prob_, (H0).w, s0.w); \
    s1.x = fmaf(prob_, (H1).x, s1.x); s1.y = fmaf(prob_, (H1).y, s1.y); \
    s1.z = fmaf(prob_, (H1).z, s1.z); s1.w = fmaf(prob_, (H1).w, s1.w); \
    s2.x = fmaf(prob_, (H2).x, s2.x); s2.y = fmaf(prob_, (H2).y, s2.y); \
    s2.z = fmaf(prob_, (H2).z, s2.z); s2.w = fmaf(prob_, (H2).w, s2.w); \
    s3.x = fmaf(prob_, (H3).x, s3.x); s3.y = fmaf(prob_, (H3).y, s3.y); \
    s3.z = fmaf(prob_, (H3).z, s3.z); s3.w = fmaf(prob_, (H3).w, s3.w); \
} while (0)

    LOADROW(0, hA0,hA1,hA2,hA3, wA0,wA1,wA2,wA3);
    {
        int t1c = min(1, len - 1);
        LOADROW(t1c, hB0,hB1,hB2,hB3, wB0,wB1,wB2,wB3);
    }
    int t = 0;
    while (true) {
        int tn = min(t + 2, len - 1);
        LOADROW(tn, hC0,hC1,hC2,hC3, wC0,wC1,wC2,wC3);
        STEP(t, hA0,hA1,hA2,hA3, wA0,wA1,wA2,wA3);
        ++t; if (t >= len) break;
        tn = min(t + 2, len - 1);
        LOADROW(tn, hA0,hA1,hA2,hA3, wA0,wA1,wA2,wA3);
        STEP(t, hB0,hB1,hB2,hB3, wB0,wB1,wB2,wB3);
        ++t; if (t >= len) break;
        tn = min(t + 2, len - 1);
        LOADROW(tn, hB0,hB1,hB2,hB3, wB0,wB1,wB2,wB3);
        STEP(t, hC0,hC1,hC2,hC3, wC0,wC1,wC2,wC3);
        ++t; if (t >= len) break;
    }
#undef LOADROW
#undef DOT4
#undef STEP
}

// ---------- launch ----------
extern "C" void kernel_launch(void* const* d_in, const int* in_sizes, int n_in,
                              void* d_out, int out_size, void* d_ws, size_t ws_size,
                              hipStream_t stream)
{
    const float* sent      = (const float*)d_in[0];
    const float* fc_w      = (const float*)d_in[1];
    const float* fc_b      = (const float*)d_in[2];
    const float* content_w = (const float*)d_in[3];
    const float* sal_w     = (const float*)d_in[4];
    const float* nov_w     = (const float*)d_in[5];
    const float* abs_emb   = (const float*)d_in[6];
    const float* rel_emb   = (const float*)d_in[7];
    const float* abs_w     = (const float*)d_in[8];
    const float* rel_w     = (const float*)d_in[9];
    const float* bias      = (const float*)d_in[10];
    const int*   doc_lens  = (const int*)d_in[11];
    float* out = (float*)d_out;

    char* ws = (char*)d_ws;
    const size_t MB = 1024 * 1024;
    _Float16* docs_hi = (_Float16*)(ws);             // 1 MiB
    _Float16* docs_lo = (_Float16*)(ws + 1 * MB);    // 1 MiB
    _Float16* dv_hi   = (_Float16*)(ws + 2 * MB);    // 1 MiB
    _Float16* dv_lo   = (_Float16*)(ws + 3 * MB);    // 1 MiB
    float*    u       = (float*)(ws + 4 * MB);       // 2 MiB
    float*    abs_p   = (float*)(ws + 6 * MB);
    float*    rel_vals= (float*)(ws + 6 * MB + 512);
    _Float16* fcw_hi  = (_Float16*)(ws + 7 * MB);    // 2 MiB
    _Float16* fcw_lo  = (_Float16*)(ws + 9 * MB);    // 2 MiB
    _Float16* salw_hi = (_Float16*)(ws + 11 * MB);   // 2 MiB
    _Float16* salw_lo = (_Float16*)(ws + 13 * MB);   // 2 MiB
    _Float16* Bt_hi   = (_Float16*)(ws + 15 * MB);   // 2 MiB
    _Float16* Bt_lo   = (_Float16*)(ws + 17 * MB);   // 2 MiB
    int*      prefix  = (int*)(ws + 19 * MB);        // 513 ints
    float*    hWn     = (float*)(ws + 20 * MB);      // 200 MiB (compacted)

    // 0) prefix sums of doc_lens
    prefix_kernel<<<dim3(1), 64, 0, stream>>>(doc_lens, prefix);

    // 1) docs masked mean + split
    docs_kernel<<<dim3(B_), 256, 0, stream>>>(sent, doc_lens, docs_hi, docs_lo);

    // 2) embedding dots
    emb_kernel<<<dim3(1), 128, 0, stream>>>(abs_emb, rel_emb, abs_w, rel_w, abs_p, rel_vals);

    // 3) split fc_w / sal_w (already [N,K] layout)
    wsplit_kernel<<<dim3(2 * D_ * D_ / (256 * 4)), 256, 0, stream>>>(
        fc_w, sal_w, fcw_hi, fcw_lo, salw_hi, salw_lo);

    // 4) transpose + split nov_w
    convert_b<<<dim3(32, 32), 256, 0, stream>>>(nov_w, Bt_hi, Bt_lo);

    // 5) hWn = sent @ nov_w over COMPACTED rows (XCD-swizzled 1D grid)
    gemm_hWn<<<dim3(3200), 256, 0, stream>>>(sent, Bt_hi, Bt_lo, hWn, prefix);

    // 6) doc_vec = tanh(docs @ fc_w^T + fc_b) -> f16 pair
    gemm_ms<1><<<dim3(D_ / 128, B_ / 128), 256, 0, stream>>>(
        docs_hi, docs_lo, fcw_hi, fcw_lo, fc_b, nullptr, dv_hi, dv_lo);

    // 7) u = doc_vec @ sal_w^T + content_w -> fp32
    gemm_ms<2><<<dim3(D_ / 128, B_ / 128), 256, 0, stream>>>(
        dv_hi, dv_lo, salw_hi, salw_lo, content_w, u, nullptr, nullptr);

    // 8) scan: one wave per batch (compacted hWn base)
    scan_kernel<<<dim3(B_), 64, 0, stream>>>(
        sent, hWn, u, abs_p, rel_vals, bias, doc_lens, prefix, out);
}

// Round 9
// 606.453 us; speedup vs baseline: 1.5732x; 1.0259x over previous
//
#include <hip/hip_runtime.h>
#include <math.h>

#define B_ 512
#define L_ 100
#define D_ 1024
#define POS_DIM_ 50
#define GM 51200
#define GN 1024
#define GK 1024
#define LDT 40   // padded LDS row stride (halfwords) for A tiles in gemm_hWn

// preproc fused-grid layout
#define PP_DOCS0    0
#define PP_CONV0    512
#define PP_WSPLIT0  1536
#define PP_EMB      3584
#define PP_PREFIX   3585
#define PP_NBLKS    3586

typedef _Float16 half8 __attribute__((ext_vector_type(8)));
typedef _Float16 half4 __attribute__((ext_vector_type(4)));
typedef float floatx4 __attribute__((ext_vector_type(4)));

// ---------- fast device math ----------
__device__ __forceinline__ float fast_tanh(float x) {
    float e = __expf(2.0f * x);
    return 1.0f - 2.0f * __builtin_amdgcn_rcpf(e + 1.0f);
}
__device__ __forceinline__ float fast_sigmoid(float x) {
    return __builtin_amdgcn_rcpf(1.0f + __expf(-x));
}

// async global->LDS, 16B per lane; lds base must be wave-uniform
__device__ __forceinline__ void gll16(const void* g, void* l) {
    __builtin_amdgcn_global_load_lds(
        (const __attribute__((address_space(1))) void*)g,
        (__attribute__((address_space(3))) void*)l, 16, 0, 0);
}

// ---------- Fused preprocessing kernel (was 5 separate launches) ----------
// Block-uniform branch on blockIdx.x; each sub-body identical to its former
// standalone kernel. Saves 4 launch gaps + packs the GPU (sub-jobs run
// concurrently instead of serially under-utilizing it).
__global__ __launch_bounds__(256) void preproc(
    const float* __restrict__ sent, const int* __restrict__ doc_lens,
    _Float16* __restrict__ docs_hi, _Float16* __restrict__ docs_lo,
    const float* __restrict__ abs_emb, const float* __restrict__ rel_emb,
    const float* __restrict__ abs_w, const float* __restrict__ rel_w,
    float* __restrict__ abs_p, float* __restrict__ rel_vals,
    const float* __restrict__ fc_w, const float* __restrict__ sal_w,
    _Float16* __restrict__ fcw_hi, _Float16* __restrict__ fcw_lo,
    _Float16* __restrict__ salw_hi, _Float16* __restrict__ salw_lo,
    const float* __restrict__ nov_w,
    _Float16* __restrict__ Bt_hi, _Float16* __restrict__ Bt_lo,
    int* __restrict__ prefix)
{
    int bx = blockIdx.x;
    int tid = threadIdx.x;

    if (bx < PP_CONV0) {
        // ---- docs masked mean + f16 hi/lo split ----
        int b = bx;
        int len = doc_lens[b];
        float inv = 1.0f / (float)len;
        const float* p = sent + (size_t)b * L_ * D_ + tid * 4;
        float4 acc = {0.f, 0.f, 0.f, 0.f};
        float4 acc2 = {0.f, 0.f, 0.f, 0.f};
        int l = 0;
        for (; l + 1 < len; l += 2) {
            float4 v0 = *(const float4*)(p + (size_t)l * D_);
            float4 v1 = *(const float4*)(p + (size_t)(l + 1) * D_);
            acc.x += v0.x; acc.y += v0.y; acc.z += v0.z; acc.w += v0.w;
            acc2.x += v1.x; acc2.y += v1.y; acc2.z += v1.z; acc2.w += v1.w;
        }
        if (l < len) {
            float4 v0 = *(const float4*)(p + (size_t)l * D_);
            acc.x += v0.x; acc.y += v0.y; acc.z += v0.z; acc.w += v0.w;
        }
        acc.x += acc2.x; acc.y += acc2.y; acc.z += acc2.z; acc.w += acc2.w;
        float a[4] = {acc.x * inv, acc.y * inv, acc.z * inv, acc.w * inv};
        half4 h, lo;
        #pragma unroll
        for (int i = 0; i < 4; ++i) {
            _Float16 hi = (_Float16)a[i];
            h[i] = hi;
            lo[i] = (_Float16)(a[i] - (float)hi);
        }
        *(half4*)(docs_hi + (size_t)b * D_ + tid * 4) = h;
        *(half4*)(docs_lo + (size_t)b * D_ + tid * 4) = lo;
    } else if (bx < PP_WSPLIT0) {
        // ---- transpose + f16 hi/lo split of nov_w ----
        __shared__ float ld[32][33];
        int idx = bx - PP_CONV0;
        int k0 = (idx & 31) * 32, n0 = (idx >> 5) * 32;
        int r  = tid >> 3;
        int c4 = (tid & 7) * 4;
        float4 v = *(const float4*)(nov_w + (size_t)(k0 + r) * D_ + n0 + c4);
        ld[r][c4] = v.x; ld[r][c4 + 1] = v.y; ld[r][c4 + 2] = v.z; ld[r][c4 + 3] = v.w;
        __syncthreads();
        half4 h, l;
        #pragma unroll
        for (int i = 0; i < 4; ++i) {
            float x = ld[c4 + i][r];
            _Float16 hi = (_Float16)x;
            h[i] = hi;
            l[i] = (_Float16)(x - (float)hi);
        }
        *(half4*)(Bt_hi + (size_t)(n0 + r) * D_ + k0 + c4) = h;
        *(half4*)(Bt_lo + (size_t)(n0 + r) * D_ + k0 + c4) = l;
    } else if (bx < PP_EMB) {
        // ---- f16 hi/lo split of fc_w and sal_w ----
        int id = (bx - PP_WSPLIT0) * 256 + tid;
        int base = id * 4;
        const int NN = D_ * D_;
        const float* src; _Float16* dh; _Float16* dl; int off;
        if (base < NN) { src = fc_w; dh = fcw_hi; dl = fcw_lo; off = base; }
        else           { src = sal_w; dh = salw_hi; dl = salw_lo; off = base - NN; }
        float4 v = *(const float4*)(src + off);
        float a[4] = {v.x, v.y, v.z, v.w};
        half4 h, lo;
        #pragma unroll
        for (int i = 0; i < 4; ++i) {
            _Float16 hi = (_Float16)a[i];
            h[i] = hi;
            lo[i] = (_Float16)(a[i] - (float)hi);
        }
        *(half4*)(dh + off) = h;
        *(half4*)(dl + off) = lo;
    } else if (bx == PP_EMB) {
        // ---- tiny embedding dots ----
        int t = tid;
        if (t < L_) {
            float a = 0.f;
            for (int j = 0; j < POS_DIM_; ++j) a += abs_emb[t * POS_DIM_ + j] * abs_w[j];
            abs_p[t] = a;
        }
        if (t < 10) {
            float r = 0.f;
            for (int j = 0; j < POS_DIM_; ++j) r += rel_emb[t * POS_DIM_ + j] * rel_w[j];
            rel_vals[t] = r;
        }
    } else {
        // ---- prefix sum of doc_lens (wave 0 only) ----
        if (tid < 64) {
            int lane = tid;
            int4 a = ((const int4*)doc_lens)[lane * 2];
            int4 b = ((const int4*)doc_lens)[lane * 2 + 1];
            int v0 = a.x, v1 = a.y, v2 = a.z, v3 = a.w;
            int v4 = b.x, v5 = b.y, v6 = b.z, v7 = b.w;
            int local = v0 + v1 + v2 + v3 + v4 + v5 + v6 + v7;
            int inc = local;
            #pragma unroll
            for (int off = 1; off < 64; off <<= 1) {
                int t = __shfl_up(inc, off);
                if (lane >= off) inc += t;
            }
            int run = inc - local;
            int o0 = run;            run += v0;
            int o1 = run;            run += v1;
            int o2 = run;            run += v2;
            int o3 = run;            run += v3;
            int o4 = run;            run += v4;
            int o5 = run;            run += v5;
            int o6 = run;            run += v6;
            int o7 = run;
            int base = lane * 8;
            prefix[base]     = o0; prefix[base + 1] = o1;
            prefix[base + 2] = o2; prefix[base + 3] = o3;
            prefix[base + 4] = o4; prefix[base + 5] = o5;
            prefix[base + 6] = o6; prefix[base + 7] = o7;
            if (lane == 63) prefix[512] = inc;
        }
    }
}

// ---------- Kernel 5: MFMA 3-pass f16-split GEMM for small GEMMs ----------
// A (hi/lo) [M,K] f16, B (hi/lo) [N,K] f16; all staging via global_load_lds.
// EPI 1: v = tanh(acc+X[n]) -> write f16 hi/lo pair (Oh, Ol)
// EPI 2: v = acc+X[n]       -> write fp32 O
template<int EPI>
__global__ __launch_bounds__(256, 2) void gemm_ms(
    const _Float16* __restrict__ Ah, const _Float16* __restrict__ Al,
    const _Float16* __restrict__ Bh, const _Float16* __restrict__ Bl,
    const float* __restrict__ X, float* __restrict__ O,
    _Float16* __restrict__ Oh, _Float16* __restrict__ Ol)
{
    __shared__ _Float16 sAh[128 * 32];
    __shared__ _Float16 sAl[128 * 32];
    __shared__ _Float16 sBh[128 * 32];
    __shared__ _Float16 sBl[128 * 32];

    int tid = threadIdx.x;
    int wave = tid >> 6, lane = tid & 63;
    int n0 = blockIdx.x * 128, m0 = blockIdx.y * 128;
    int wm = (wave >> 1) * 64, wn = (wave & 1) * 64;
    int tm = lane & 15, quad = lane >> 4;

    floatx4 acc[4][4];
    #pragma unroll
    for (int i = 0; i < 4; ++i)
        #pragma unroll
        for (int j = 0; j < 4; ++j)
            acc[i][j] = (floatx4){0.f, 0.f, 0.f, 0.f};

    int grow = lane >> 2;          // 0..15
    int gcol = (lane & 3) * 8;     // halfword offset
    const _Float16* pAh = Ah + (size_t)(m0 + wave * 32 + grow) * GK + gcol;
    const _Float16* pAl = Al + (size_t)(m0 + wave * 32 + grow) * GK + gcol;
    const _Float16* pBh = Bh + (size_t)(n0 + wave * 32 + grow) * GK + gcol;
    const _Float16* pBl = Bl + (size_t)(n0 + wave * 32 + grow) * GK + gcol;
    _Float16* lAh = sAh + wave * 32 * 32;
    _Float16* lAl = sAl + wave * 32 * 32;
    _Float16* lBh = sBh + wave * 32 * 32;
    _Float16* lBl = sBl + wave * 32 * 32;

    #pragma unroll 1
    for (int k0 = 0; k0 < GK; k0 += 32) {
        __syncthreads();   // previous iteration's fragment reads complete
        gll16(pAh + k0, lAh);
        gll16(pAh + 16 * GK + k0, lAh + 16 * 32);
        gll16(pAl + k0, lAl);
        gll16(pAl + 16 * GK + k0, lAl + 16 * 32);
        gll16(pBh + k0, lBh);
        gll16(pBh + 16 * GK + k0, lBh + 16 * 32);
        gll16(pBl + k0, lBl);
        gll16(pBl + 16 * GK + k0, lBl + 16 * 32);
        __syncthreads();   // drains vmcnt(0): LDS tile ready

        half8 fah[4], fal[4], fbh[4], fbl[4];
        #pragma unroll
        for (int mt = 0; mt < 4; ++mt) {
            int base = (wm + mt * 16 + tm) * 32 + quad * 8;
            fah[mt] = *(const half8*)(sAh + base);
            fal[mt] = *(const half8*)(sAl + base);
        }
        #pragma unroll
        for (int nt = 0; nt < 4; ++nt) {
            int base = (wn + nt * 16 + tm) * 32 + quad * 8;
            fbh[nt] = *(const half8*)(sBh + base);
            fbl[nt] = *(const half8*)(sBl + base);
        }
        #pragma unroll
        for (int mt = 0; mt < 4; ++mt)
            #pragma unroll
            for (int nt = 0; nt < 4; ++nt) {
                acc[mt][nt] = __builtin_amdgcn_mfma_f32_16x16x32_f16(
                    fah[mt], fbh[nt], acc[mt][nt], 0, 0, 0);
                acc[mt][nt] = __builtin_amdgcn_mfma_f32_16x16x32_f16(
                    fah[mt], fbl[nt], acc[mt][nt], 0, 0, 0);
                acc[mt][nt] = __builtin_amdgcn_mfma_f32_16x16x32_f16(
                    fal[mt], fbh[nt], acc[mt][nt], 0, 0, 0);
            }
    }

    #pragma unroll
    for (int mt = 0; mt < 4; ++mt) {
        #pragma unroll
        for (int nt = 0; nt < 4; ++nt) {
            int col = n0 + wn + nt * 16 + tm;
            int rowb = m0 + wm + mt * 16 + quad * 4;
            float xv = X[col];
            #pragma unroll
            for (int r = 0; r < 4; ++r) {
                float v = acc[mt][nt][r];
                if (EPI == 1) {
                    v = tanhf(v + xv);
                    _Float16 hi = (_Float16)v;
                    Oh[(size_t)(rowb + r) * GN + col] = hi;
                    Ol[(size_t)(rowb + r) * GN + col] = (_Float16)(v - (float)hi);
                } else {
                    O[(size_t)(rowb + r) * GN + col] = v + xv;
                }
            }
        }
    }
}

// ---------- Kernel 6: MFMA f16-split GEMM: hWn = sent @ nov_w (COMPACTED) ----------
// EXACT round-2 K-loop schedule (frozen). M-space compacted over valid
// (b, t<len) rows via prefix[]; padding rows (~45%) skipped. (r7: 178 us)
__global__ __launch_bounds__(256, 2) void gemm_hWn(
    const float* __restrict__ A, const _Float16* __restrict__ Bt_hi,
    const _Float16* __restrict__ Bt_lo, float* __restrict__ C,
    const int* __restrict__ prefix)
{
    __shared__ _Float16 As_hi[128 * LDT];
    __shared__ _Float16 As_lo[128 * LDT];
    __shared__ _Float16 Bs_hi[128 * 32];
    __shared__ _Float16 Bs_lo[128 * 32];

    int tid  = threadIdx.x;
    int wave = tid >> 6, lane = tid & 63;
    int d = blockIdx.x;
    int islab = d & 7, nblk = (d >> 3) & 7, g = d >> 6;
    int m0 = (g * 8 + islab) * 128;
    int n0 = nblk * 128;

    int total = prefix[512];
    if (m0 >= total) return;        // block-uniform: no barrier divergence

    int wm = (wave >> 1) * 64, wn = (wave & 1) * 64;
    int tm   = lane & 15;
    int quad = lane >> 4;

    floatx4 acc[4][4];
    #pragma unroll
    for (int i = 0; i < 4; ++i)
        #pragma unroll
        for (int j = 0; j < 4; ++j)
            acc[i][j] = (floatx4){0.f, 0.f, 0.f, 0.f};

    // A staging: thread covers (compacted row, 16-elem k-half).
    int sr = tid >> 1;
    int sh = tid & 1;
    const float* Ap;
    {
        int r = m0 + sr;
        if (r > total - 1) r = total - 1;      // boundary tile clamp (rows unused)
        int lo = 0, hi = 512;
        while (hi - lo > 1) {
            int mid = (lo + hi) >> 1;
            if (prefix[mid] <= r) lo = mid; else hi = mid;
        }
        int t = r - prefix[lo];
        Ap = A + (size_t)(lo * L_ + t) * GK + sh * 16;
    }
    int sbase = sr * LDT + sh * 16;

    // B staging via gll: wave covers rows [wave*32, wave*32+32)
    int grow = lane >> 2;
    int gswz = ((lane & 3) ^ ((lane >> 3) & 3)) * 8;   // halfword offset
    const _Float16* pBh = Bt_hi + (size_t)(n0 + wave * 32 + grow) * GK + gswz;
    const _Float16* pBl = Bt_lo + (size_t)(n0 + wave * 32 + grow) * GK + gswz;
    _Float16* lBh = Bs_hi + wave * 32 * 32;
    _Float16* lBl = Bs_lo + wave * 32 * 32;

    #pragma unroll 1
    for (int k0 = 0; k0 < GK; k0 += 32) {
        float4 a0 = *(const float4*)(Ap + k0);
        float4 a1 = *(const float4*)(Ap + k0 + 4);
        float4 a2 = *(const float4*)(Ap + k0 + 8);
        float4 a3 = *(const float4*)(Ap + k0 + 12);

        half8 ah0, ah1, al0, al1;
        float af[16] = {a0.x, a0.y, a0.z, a0.w, a1.x, a1.y, a1.z, a1.w,
                        a2.x, a2.y, a2.z, a2.w, a3.x, a3.y, a3.z, a3.w};
        #pragma unroll
        for (int i = 0; i < 8; ++i) {
            _Float16 h = (_Float16)af[i];
            ah0[i] = h;
            al0[i] = (_Float16)(af[i] - (float)h);
        }
        #pragma unroll
        for (int i = 0; i < 8; ++i) {
            _Float16 h = (_Float16)af[8 + i];
            ah1[i] = h;
            al1[i] = (_Float16)(af[8 + i] - (float)h);
        }

        __syncthreads();   // previous iteration's fragment reads complete
        // B DMA into LDS (linear dest; source chunk pre-swizzled)
        gll16(pBh + k0, lBh);
        gll16(pBh + 16 * GK + k0, lBh + 16 * 32);
        gll16(pBl + k0, lBl);
        gll16(pBl + 16 * GK + k0, lBl + 16 * 32);
        // A stores
        *(half8*)(As_hi + sbase)     = ah0;
        *(half8*)(As_hi + sbase + 8) = ah1;
        *(half8*)(As_lo + sbase)     = al0;
        *(half8*)(As_lo + sbase + 8) = al1;
        __syncthreads();   // drains vmcnt (gll) + lgkm (stores)

        half8 fa_hi[4], fa_lo[4], fb_hi[4], fb_lo[4];
        #pragma unroll
        for (int mt = 0; mt < 4; ++mt) {
            int row = (wm + mt * 16 + tm) * LDT + quad * 8;
            fa_hi[mt] = *(const half8*)(As_hi + row);
            fa_lo[mt] = *(const half8*)(As_lo + row);
        }
        #pragma unroll
        for (int nt = 0; nt < 4; ++nt) {
            int row = wn + nt * 16 + tm;
            int rbase = row * 32 + ((quad ^ ((row >> 1) & 3)) << 3);
            fb_hi[nt] = *(const half8*)(Bs_hi + rbase);
            fb_lo[nt] = *(const half8*)(Bs_lo + rbase);
        }
        #pragma unroll
        for (int mt = 0; mt < 4; ++mt)
            #pragma unroll
            for (int nt = 0; nt < 4; ++nt) {
                acc[mt][nt] = __builtin_amdgcn_mfma_f32_16x16x32_f16(
                    fa_hi[mt], fb_hi[nt], acc[mt][nt], 0, 0, 0);
                acc[mt][nt] = __builtin_amdgcn_mfma_f32_16x16x32_f16(
                    fa_hi[mt], fb_lo[nt], acc[mt][nt], 0, 0, 0);
                acc[mt][nt] = __builtin_amdgcn_mfma_f32_16x16x32_f16(
                    fa_lo[mt], fb_hi[nt], acc[mt][nt], 0, 0, 0);
            }
    }

    #pragma unroll
    for (int mt = 0; mt < 4; ++mt) {
        #pragma unroll
        for (int nt = 0; nt < 4; ++nt) {
            int col = n0 + wn + nt * 16 + tm;
            int rowb = m0 + wm + mt * 16 + quad * 4;
            #pragma unroll
            for (int r = 0; r < 4; ++r)
                C[(size_t)(rowb + r) * GN + col] = acc[mt][nt][r];
        }
    }
}

// ---------- Kernel 7: scan — one wave per batch, all-register ----------
// r8 version (single combined butterfly, 4-way ILP dots, depth-2 prefetch).
// Named registers only (rule #20). hWn compacted via prefix[b].
__global__ __launch_bounds__(64) void scan_kernel(
    const float* __restrict__ sent, const float* __restrict__ hWn,
    const float* __restrict__ u, const float* __restrict__ abs_p,
    const float* __restrict__ rel_vals, const float* __restrict__ bias,
    const int* __restrict__ doc_lens, const int* __restrict__ prefix,
    float* __restrict__ out)
{
    int b = blockIdx.x;
    int lane = threadIdx.x;
    int len = doc_lens[b];
    float lenf = (float)len;

    for (int l = len + lane; l < L_; l += 64) out[b * L_ + l] = 0.f;

    // lane owns cols {lane*4 + j*256 : j=0..3, +0..3}
    const float* ub = u + (size_t)b * D_ + lane * 4;
    float4 ur0 = *(const float4*)(ub);
    float4 ur1 = *(const float4*)(ub + 256);
    float4 ur2 = *(const float4*)(ub + 512);
    float4 ur3 = *(const float4*)(ub + 768);

    float4 s0 = {0.f,0.f,0.f,0.f}, s1 = {0.f,0.f,0.f,0.f};
    float4 s2 = {0.f,0.f,0.f,0.f}, s3 = {0.f,0.f,0.f,0.f};

    const float* sb = sent + (size_t)b * L_ * D_ + lane * 4;
    const float* wb = hWn  + (size_t)prefix[b] * D_ + lane * 4;   // compacted
    float biasv = bias[0];

    float4 hA0, hA1, hA2, hA3, wA0, wA1, wA2, wA3;
    float4 hB0, hB1, hB2, hB3, wB0, wB1, wB2, wB3;
    float4 hC0, hC1, hC2, hC3, wC0, wC1, wC2, wC3;

#define LOADROW(row, H0,H1,H2,H3, W0,W1,W2,W3) do { \
    const float* ph_ = sb + (size_t)(row) * D_; \
    const float* pw_ = wb + (size_t)(row) * D_; \
    H0 = *(const float4*)(ph_);       W0 = *(const float4*)(pw_); \
    H1 = *(const float4*)(ph_ + 256); W1 = *(const float4*)(pw_ + 256); \
    H2 = *(const float4*)(ph_ + 512); W2 = *(const float4*)(pw_ + 512); \
    H3 = *(const float4*)(ph_ + 768); W3 = *(const float4*)(pw_ + 768); \
} while (0)

#define DOT4(acc_, X, Y) do { \
    acc_ = fmaf((X).x, (Y).x, acc_); acc_ = fmaf((X).y, (Y).y, acc_); \
    acc_ = fmaf((X).z, (Y).z, acc_); acc_ = fmaf((X).w, (Y).w, acc_); \
} while (0)

#define STEP(t, H0,H1,H2,H3, W0,W1,W2,W3) do { \
    float4 t0_, t1_, t2_, t3_; \
    t0_.x = fast_tanh(s0.x); t0_.y = fast_tanh(s0.y); t0_.z = fast_tanh(s0.z); t0_.w = fast_tanh(s0.w); \
    t1_.x = fast_tanh(s1.x); t1_.y = fast_tanh(s1.y); t1_.z = fast_tanh(s1.z); t1_.w = fast_tanh(s1.w); \
    t2_.x = fast_tanh(s2.x); t2_.y = fast_tanh(s2.y); t2_.z = fast_tanh(s2.z); t2_.w = fast_tanh(s2.w); \
    t3_.x = fast_tanh(s3.x); t3_.y = fast_tanh(s3.y); t3_.z = fast_tanh(s3.z); t3_.w = fast_tanh(s3.w); \
    float p0_ = 0.f, p1_ = 0.f, p2_ = 0.f, p3_ = 0.f; \
    float q0_ = 0.f, q1_ = 0.f, q2_ = 0.f, q3_ = 0.f; \
    DOT4(p0_, W0, t0_); DOT4(p1_, W1, t1_); DOT4(p2_, W2, t2_); DOT4(p3_, W3, t3_); \
    DOT4(q0_, H0, ur0); DOT4(q1_, H1, ur1); DOT4(q2_, H2, ur2); DOT4(q3_, H3, ur3); \
    float d_ = ((q0_ + q1_) + (q2_ + q3_)) - ((p0_ + p1_) + (p2_ + p3_)); \
    _Pragma("unroll") \
    for (int off_ = 32; off_; off_ >>= 1) d_ += __shfl_xor(d_, off_); \
    int ridx_ = (int)rintf((float)((t) + 1) * 9.0f / lenf); \
    ridx_ = min(max(ridx_, 0), 9); \
    float pre_ = d_ + abs_p[(t)] + rel_vals[ridx_] + biasv; \
    float prob_ = fast_sigmoid(pre_); \
    if (lane == 0) out[b * L_ + (t)] = prob_; \
    s0.x = fmaf(prob_, (H0).x, s0.x); s0.y = fmaf(prob_, (H0).y, s0.y); \
    s0.z = fmaf(prob_, (H0).z, s0.z); s0.w = fmaf(prob_, (H0).w, s0.w); \
    s1.x = fmaf(prob_, (H1).x, s1.x); s1.y = fmaf(prob_, (H1).y, s1.y); \
    s1.z = fmaf(prob_, (H1).z, s1.z); s1.w = fmaf(prob_, (H1).w, s1.w); \
    s2.x = fmaf(prob_, (H2).x, s2.x); s2.y = fmaf(prob_, (H2).y, s2.y); \
    s2.z = fmaf(prob_, (H2).z, s2.z); s2.w = fmaf(prob_, (H2).w, s2.w); \
    s3.x = fmaf(prob_, (H3).x, s3.x); s3.y = fmaf(prob_, (H3).y, s3.y); \
    s3.z = fmaf(prob_, (H3).z, s3.z); s3.w = fmaf(prob_, (H3).w, s3.w); \
} while (0)

    LOADROW(0, hA0,hA1,hA2,hA3, wA0,wA1,wA2,wA3);
    {
        int t1c = min(1, len - 1);
        LOADROW(t1c, hB0,hB1,hB2,hB3, wB0,wB1,wB2,wB3);
    }
    int t = 0;
    while (true) {
        int tn = min(t + 2, len - 1);
        LOADROW(tn, hC0,hC1,hC2,hC3, wC0,wC1,wC2,wC3);
        STEP(t, hA0,hA1,hA2,hA3, wA0,wA1,wA2,wA3);
        ++t; if (t >= len) break;
        tn = min(t + 2, len - 1);
        LOADROW(tn, hA0,hA1,hA2,hA3, wA0,wA1,wA2,wA3);
        STEP(t, hB0,hB1,hB2,hB3, wB0,wB1,wB2,wB3);
        ++t; if (t >= len) break;
        tn = min(t + 2, len - 1);
        LOADROW(tn, hB0,hB1,hB2,hB3, wB0,wB1,wB2,wB3);
        STEP(t, hC0,hC1,hC2,hC3, wC0,wC1,wC2,wC3);
        ++t; if (t >= len) break;
    }
#undef LOADROW
#undef DOT4
#undef STEP
}

// ---------- launch ----------
extern "C" void kernel_launch(void* const* d_in, const int* in_sizes, int n_in,
                              void* d_out, int out_size, void* d_ws, size_t ws_size,
                              hipStream_t stream)
{
    const float* sent      = (const float*)d_in[0];
    const float* fc_w      = (const float*)d_in[1];
    const float* fc_b      = (const float*)d_in[2];
    const float* content_w = (const float*)d_in[3];
    const float* sal_w     = (const float*)d_in[4];
    const float* nov_w     = (const float*)d_in[5];
    const float* abs_emb   = (const float*)d_in[6];
    const float* rel_emb   = (const float*)d_in[7];
    const float* abs_w     = (const float*)d_in[8];
    const float* rel_w     = (const float*)d_in[9];
    const float* bias      = (const float*)d_in[10];
    const int*   doc_lens  = (const int*)d_in[11];
    float* out = (float*)d_out;

    char* ws = (char*)d_ws;
    const size_t MB = 1024 * 1024;
    _Float16* docs_hi = (_Float16*)(ws);             // 1 MiB
    _Float16* docs_lo = (_Float16*)(ws + 1 * MB);    // 1 MiB
    _Float16* dv_hi   = (_Float16*)(ws + 2 * MB);    // 1 MiB
    _Float16* dv_lo   = (_Float16*)(ws + 3 * MB);    // 1 MiB
    float*    u       = (float*)(ws + 4 * MB);       // 2 MiB
    float*    abs_p   = (float*)(ws + 6 * MB);
    float*    rel_vals= (float*)(ws + 6 * MB + 512);
    _Float16* fcw_hi  = (_Float16*)(ws + 7 * MB);    // 2 MiB
    _Float16* fcw_lo  = (_Float16*)(ws + 9 * MB);    // 2 MiB
    _Float16* salw_hi = (_Float16*)(ws + 11 * MB);   // 2 MiB
    _Float16* salw_lo = (_Float16*)(ws + 13 * MB);   // 2 MiB
    _Float16* Bt_hi   = (_Float16*)(ws + 15 * MB);   // 2 MiB
    _Float16* Bt_lo   = (_Float16*)(ws + 17 * MB);   // 2 MiB
    int*      prefix  = (int*)(ws + 19 * MB);        // 513 ints
    float*    hWn     = (float*)(ws + 20 * MB);      // 200 MiB (compacted)

    // 1) all preprocessing in ONE launch (docs/convert/wsplit/emb/prefix)
    preproc<<<dim3(PP_NBLKS), 256, 0, stream>>>(
        sent, doc_lens, docs_hi, docs_lo,
        abs_emb, rel_emb, abs_w, rel_w, abs_p, rel_vals,
        fc_w, sal_w, fcw_hi, fcw_lo, salw_hi, salw_lo,
        nov_w, Bt_hi, Bt_lo, prefix);

    // 2) doc_vec = tanh(docs @ fc_w^T + fc_b) -> f16 pair
    gemm_ms<1><<<dim3(D_ / 128, B_ / 128), 256, 0, stream>>>(
        docs_hi, docs_lo, fcw_hi, fcw_lo, fc_b, nullptr, dv_hi, dv_lo);

    // 3) u = doc_vec @ sal_w^T + content_w -> fp32
    gemm_ms<2><<<dim3(D_ / 128, B_ / 128), 256, 0, stream>>>(
        dv_hi, dv_lo, salw_hi, salw_lo, content_w, u, nullptr, nullptr);

    // 4) hWn = sent @ nov_w over COMPACTED rows (XCD-swizzled 1D grid)
    gemm_hWn<<<dim3(3200), 256, 0, stream>>>(sent, Bt_hi, Bt_lo, hWn, prefix);

    // 5) scan: one wave per batch (compacted hWn base)
    scan_kernel<<<dim3(B_), 64, 0, stream>>>(
        sent, hWn, u, abs_p, rel_vals, bias, doc_lens, prefix, out);
}